// Round 1
// baseline (26258.252 us; speedup 1.0000x reference)
//
#include <hip/hip_runtime.h>
#include <cstdint>
#include <cstddef>

#define TT 2048
#define BB 4
#define HDIM 512
#define NH 4
#define DH 128
#define LAYERS 4
#define WINDOW 606

// ---------------- reduction helpers ----------------
__device__ __forceinline__ float wred_sum(float v) {
#pragma unroll
  for (int off = 32; off; off >>= 1) v += __shfl_xor(v, off, 64);
  return v;
}
__device__ __forceinline__ float wred_max(float v) {
#pragma unroll
  for (int off = 32; off; off >>= 1) v = fmaxf(v, __shfl_xor(v, off, 64));
  return v;
}
__device__ __forceinline__ float gelu_exact(float x) {
  return 0.5f * x * (1.0f + erff(x * 0.70710678118654752f));
}

// ---------------- input embed: u_aug @ W_in + b + pos_enc ----------------
__global__ __launch_bounds__(256) void embed_kernel(
    const float* __restrict__ u, const float* __restrict__ y,
    const float* __restrict__ W_in, const float* __restrict__ b_in,
    float* __restrict__ X) {
  const int row = blockIdx.x;          // b*T + t
  const int b = row >> 11;             // T = 2048
  const int t = row & 2047;
  const int tid = threadIdx.x;
  __shared__ float ua[24];
  if (tid < 8)       ua[tid] = u[((b << 3) + tid) * TT + t];
  else if (tid < 16) ua[tid] = 0.0f;   // y_aug (phy rollout) is zeros
  else if (tid < 24) ua[tid] = (t < 30) ? y[((b << 3) + (tid - 16)) * TT + t] : 0.0f;
  __syncthreads();
#pragma unroll
  for (int c0 = 0; c0 < 2; ++c0) {
    const int c = c0 * 256 + tid;
    float s = b_in[c];
#pragma unroll
    for (int k = 0; k < 24; ++k) s += ua[k] * W_in[k * HDIM + c];
    // pe[t, 2i] = sin(t*div_i), pe[t, 2i+1] = cos(t*div_i), div_i = exp(-2i*ln(1e4)/512)
    const float dv = expf(-0.0179889460337f * (float)(c & ~1));
    const float arg = (float)t * dv;
    s += (c & 1) ? cosf(arg) : sinf(arg);
    X[(size_t)row * HDIM + c] = s;
  }
}

// ---------------- fp32 tiled GEMM: C[M,N] = A[M,K] @ B[K,N] + bias, optional GELU ----------------
// BM=128, BN=64, BK=16, 256 threads, 8x4 per thread. M must be %128, K %16.
template <int ACT>
__global__ __launch_bounds__(256) void gemm_bias(
    const float* __restrict__ A, const float* __restrict__ B,
    const float* __restrict__ bias, float* __restrict__ C,
    int M, int N, int K) {
  __shared__ float As[16][132];   // [k][m], padded: 132*4B = 16B-aligned rows
  __shared__ float Bs[16][64];    // [k][n]
  const int bm = blockIdx.y * 128;
  const int bn = blockIdx.x * 64;
  const int tid = threadIdx.x;
  const int tx = tid & 15, ty = tid >> 4;
  float acc[8][4] = {};
  for (int k0 = 0; k0 < K; k0 += 16) {
#pragma unroll
    for (int i = 0; i < 8; ++i) {
      const int idx = i * 256 + tid;
      const int m = idx >> 4, k = idx & 15;
      As[k][m] = A[(size_t)(bm + m) * K + k0 + k];
    }
#pragma unroll
    for (int i = 0; i < 4; ++i) {
      const int idx = i * 256 + tid;
      const int k = idx >> 6, n = idx & 63;
      Bs[k][n] = (bn + n < N) ? B[(size_t)(k0 + k) * N + bn + n] : 0.0f;
    }
    __syncthreads();
#pragma unroll
    for (int kk = 0; kk < 16; ++kk) {
      float a[8], bb[4];
#pragma unroll
      for (int i = 0; i < 8; ++i) a[i] = As[kk][ty * 8 + i];
#pragma unroll
      for (int j = 0; j < 4; ++j) bb[j] = Bs[kk][tx * 4 + j];
#pragma unroll
      for (int i = 0; i < 8; ++i)
#pragma unroll
        for (int j = 0; j < 4; ++j) acc[i][j] += a[i] * bb[j];
    }
    __syncthreads();
  }
#pragma unroll
  for (int i = 0; i < 8; ++i) {
    const int m = bm + ty * 8 + i;
#pragma unroll
    for (int j = 0; j < 4; ++j) {
      const int n = bn + tx * 4 + j;
      if (n < N) {
        float v = acc[i][j] + bias[n];
        if (ACT == 1) v = gelu_exact(v);
        C[(size_t)m * N + n] = v;
      }
    }
  }
}

// ---------------- sliding-window attention, one block per (b, head, t) ----------------
// qkv row layout: [q(512) | k(512) | v(512)], head hh occupies dims [hh*128, hh*128+128)
__global__ __launch_bounds__(256) void attn_kernel(
    const float* __restrict__ qkv, float* __restrict__ out) {
  const int t = blockIdx.x, hh = blockIdx.y, b = blockIdx.z;
  const int row = b * TT + t;
  const int tid = threadIdx.x;
  __shared__ __align__(16) float q[128];
  __shared__ float sc[608];
  __shared__ float red[4];
  __shared__ float ored[128];
  if (tid < 128) q[tid] = qkv[(size_t)row * 1536 + hh * 128 + tid];
  __syncthreads();
  const int jstart = max(0, t - (WINDOW - 1));
  const int nk = t - jstart + 1;   // <= 606
  const float scale = 0.08838834764831845f;  // 1/sqrt(128)
  for (int jj = tid; jj < nk; jj += 256) {
    const float4* k4 = (const float4*)(qkv + (size_t)(b * TT + jstart + jj) * 1536 + 512 + hh * 128);
    const float4* q4 = (const float4*)q;
    float s = 0.0f;
#pragma unroll
    for (int d = 0; d < 32; ++d) {
      const float4 kv = k4[d], qv = q4[d];
      s += qv.x * kv.x + qv.y * kv.y + qv.z * kv.z + qv.w * kv.w;
    }
    sc[jj] = s * scale;
  }
  __syncthreads();
  // block max
  float m = -1e30f;
  for (int jj = tid; jj < nk; jj += 256) m = fmaxf(m, sc[jj]);
  m = wred_max(m);
  if ((tid & 63) == 0) red[tid >> 6] = m;
  __syncthreads();
  m = fmaxf(fmaxf(red[0], red[1]), fmaxf(red[2], red[3]));
  __syncthreads();
  // exp + block sum
  float ssum = 0.0f;
  for (int jj = tid; jj < nk; jj += 256) {
    const float e = expf(sc[jj] - m);
    sc[jj] = e;
    ssum += e;
  }
  ssum = wred_sum(ssum);
  if ((tid & 63) == 0) red[tid >> 6] = ssum;
  __syncthreads();
  const float total = red[0] + red[1] + red[2] + red[3];
  // PV: two halves of threads split the key range per output dim
  const int d = tid & 127, half = tid >> 7;
  float o = 0.0f;
  for (int jj = half; jj < nk; jj += 2)
    o += sc[jj] * qkv[(size_t)(b * TT + jstart + jj) * 1536 + 1024 + hh * 128 + d];
  if (half == 1) ored[d] = o;
  __syncthreads();
  if (half == 0) out[(size_t)row * HDIM + hh * 128 + d] = (o + ored[d]) / total;
}

// ---------------- residual + LayerNorm (in-place safe per row) ----------------
template <int HAS_RES>
__global__ __launch_bounds__(128) void ln_kernel(
    const float* __restrict__ x, const float* __restrict__ r,
    const float* __restrict__ g, const float* __restrict__ be,
    float* __restrict__ out) {
  const int row = blockIdx.x, tid = threadIdx.x;
  float4 v = ((const float4*)(x + (size_t)row * HDIM))[tid];
  if (HAS_RES) {
    const float4 rv = ((const float4*)(r + (size_t)row * HDIM))[tid];
    v.x += rv.x; v.y += rv.y; v.z += rv.z; v.w += rv.w;
  }
  __shared__ float red[2];
  float s = v.x + v.y + v.z + v.w;
  s = wred_sum(s);
  if ((tid & 63) == 0) red[tid >> 6] = s;
  __syncthreads();
  const float mean = (red[0] + red[1]) * (1.0f / 512.0f);
  const float dx = v.x - mean, dy = v.y - mean, dz = v.z - mean, dw = v.w - mean;
  float s2 = dx * dx + dy * dy + dz * dz + dw * dw;
  __syncthreads();
  s2 = wred_sum(s2);
  if ((tid & 63) == 0) red[tid >> 6] = s2;
  __syncthreads();
  const float var = (red[0] + red[1]) * (1.0f / 512.0f);
  const float inv = 1.0f / sqrtf(var + 1e-5f);
  const float4 gv = ((const float4*)g)[tid];
  const float4 bv = ((const float4*)be)[tid];
  float4 o;
  o.x = dx * inv * gv.x + bv.x;
  o.y = dy * inv * gv.y + bv.y;
  o.z = dz * inv * gv.z + bv.z;
  o.w = dw * inv * gv.w + bv.w;
  ((float4*)(out + (size_t)row * HDIM))[tid] = o;
}

// ---------------- fused me3 projection + SSE loss partials ----------------
__global__ __launch_bounds__(256) void head_loss_kernel(
    const float* __restrict__ hme, const float* __restrict__ w3,
    const float* __restrict__ b3, const float* __restrict__ y,
    float* __restrict__ partials) {
  const int row = blockIdx.x;
  const int b = row >> 11, t = row & 2047;
  const int tid = threadIdx.x;
  __shared__ __align__(16) float hl[512];
  __shared__ float acc8[8];
  ((float2*)hl)[tid] = ((const float2*)(hme + (size_t)row * HDIM))[tid];
  __syncthreads();
  const int d = tid >> 5, l32 = tid & 31;  // 8 outputs x 32 lanes
  float s = 0.0f;
  for (int k = l32; k < 512; k += 32) s += hl[k] * w3[k * 8 + d];
#pragma unroll
  for (int off = 16; off; off >>= 1) s += __shfl_xor(s, off, 64);  // stays within 32-group
  if (l32 == 0) {
    const float yh = s + b3[d];
    const float diff = yh - y[((b << 3) + d) * TT + t];
    acc8[d] = diff * diff;
  }
  __syncthreads();
  if (tid == 0) {
    float tot = 0.0f;
#pragma unroll
    for (int i = 0; i < 8; ++i) tot += acc8[i];
    partials[row] = tot;
  }
}

__global__ __launch_bounds__(256) void reduce_kernel(
    const float* __restrict__ partials, float* __restrict__ out, int n) {
  float s = 0.0f;
  for (int i = threadIdx.x; i < n; i += 256) s += partials[i];
  s = wred_sum(s);
  __shared__ float red[4];
  if ((threadIdx.x & 63) == 0) red[threadIdx.x >> 6] = s;
  __syncthreads();
  if (threadIdx.x == 0) out[0] = red[0] + red[1] + red[2] + red[3];
}

// ---------------- host ----------------
extern "C" void kernel_launch(void* const* d_in, const int* in_sizes, int n_in,
                              void* d_out, int out_size, void* d_ws, size_t ws_size,
                              hipStream_t stream) {
  (void)in_sizes; (void)n_in; (void)out_size; (void)ws_size;
  const float* u     = (const float*)d_in[0];
  const float* y     = (const float*)d_in[1];
  const float* W_in  = (const float*)d_in[2];
  const float* b_in  = (const float*)d_in[3];
  const float* qkv_w = (const float*)d_in[4];
  const float* qkv_b = (const float*)d_in[5];
  const float* out_w = (const float*)d_in[6];
  const float* out_b = (const float*)d_in[7];
  const float* ff1_w = (const float*)d_in[8];
  const float* ff1_b = (const float*)d_in[9];
  const float* ff2_w = (const float*)d_in[10];
  const float* ff2_b = (const float*)d_in[11];
  const float* ln1_g = (const float*)d_in[12];
  const float* ln1_b = (const float*)d_in[13];
  const float* ln2_g = (const float*)d_in[14];
  const float* ln2_b = (const float*)d_in[15];
  const float* lnf_g = (const float*)d_in[16];
  const float* lnf_b = (const float*)d_in[17];
  const float* xm1_w = (const float*)d_in[18];
  const float* xm1_b = (const float*)d_in[19];
  const float* xm2_w = (const float*)d_in[20];
  const float* xm2_b = (const float*)d_in[21];
  const float* me1_w = (const float*)d_in[22];
  const float* me1_b = (const float*)d_in[23];
  const float* me2_w = (const float*)d_in[24];
  const float* me2_b = (const float*)d_in[25];
  const float* me3_w = (const float*)d_in[26];
  const float* me3_b = (const float*)d_in[27];

  const int M = BB * TT;  // 8192
  char* ws = (char*)d_ws;
  float* X    = (float*)(ws);                         // 16 MB [8192,512]
  float* QKV  = (float*)(ws + (size_t)(16u << 20));   // 48 MB [8192,1536]
  float* ATT  = (float*)(ws + (size_t)(64u << 20));   // 16 MB [8192,512]
  float* PRJ  = (float*)(ws + (size_t)(80u << 20));   // 16 MB [8192,512]
  float* FF   = (float*)(ws + (size_t)(96u << 20));   // 64 MB [8192,2048]
  float* XM   = (float*)(ws + (size_t)(160u << 20));  // 512 KB [8192,16]
  float* PART = (float*)(ws + (size_t)(161u << 20));  // 32 KB [8192]

  embed_kernel<<<M, 256, 0, stream>>>(u, y, W_in, b_in, X);

  for (int l = 0; l < LAYERS; ++l) {
    gemm_bias<0><<<dim3(1536 / 64, M / 128), 256, 0, stream>>>(
        X, qkv_w + (size_t)l * 512 * 1536, qkv_b + l * 1536, QKV, M, 1536, 512);
    attn_kernel<<<dim3(TT, NH, BB), 256, 0, stream>>>(QKV, ATT);
    gemm_bias<0><<<dim3(512 / 64, M / 128), 256, 0, stream>>>(
        ATT, out_w + (size_t)l * 512 * 512, out_b + l * 512, PRJ, M, 512, 512);
    ln_kernel<1><<<M, 128, 0, stream>>>(X, PRJ, ln1_g + l * 512, ln1_b + l * 512, X);
    gemm_bias<1><<<dim3(2048 / 64, M / 128), 256, 0, stream>>>(
        X, ff1_w + (size_t)l * 512 * 2048, ff1_b + l * 2048, FF, M, 2048, 512);
    gemm_bias<0><<<dim3(512 / 64, M / 128), 256, 0, stream>>>(
        FF, ff2_w + (size_t)l * 2048 * 512, ff2_b + l * 512, PRJ, M, 512, 2048);
    ln_kernel<1><<<M, 128, 0, stream>>>(X, PRJ, ln2_g + l * 512, ln2_b + l * 512, X);
  }
  ln_kernel<0><<<M, 128, 0, stream>>>(X, nullptr, lnf_g, lnf_b, X);

  gemm_bias<1><<<dim3(8, 64), 256, 0, stream>>>(X, xm1_w, xm1_b, PRJ, M, 512, 512);
  gemm_bias<0><<<dim3(1, 64), 256, 0, stream>>>(PRJ, xm2_w, xm2_b, XM, M, 16, 512);
  gemm_bias<1><<<dim3(8, 64), 256, 0, stream>>>(XM, me1_w, me1_b, ATT, M, 512, 16);
  gemm_bias<1><<<dim3(8, 64), 256, 0, stream>>>(ATT, me2_w, me2_b, PRJ, M, 512, 512);
  head_loss_kernel<<<M, 256, 0, stream>>>(PRJ, me3_w, me3_b, y, PART);
  reduce_kernel<<<1, 256, 0, stream>>>(PART, (float*)d_out, M);
}

// Round 2
// 6562.299 us; speedup vs baseline: 4.0014x; 4.0014x over previous
//
#include <hip/hip_runtime.h>
#include <cstdint>
#include <cstddef>

#define TT 2048
#define BB 4
#define HDIM 512
#define NH 4
#define DH 128
#define LAYERS 4
#define WINDOW 606

// ---------------- reduction helpers ----------------
__device__ __forceinline__ float wred_sum(float v) {
#pragma unroll
  for (int off = 32; off; off >>= 1) v += __shfl_xor(v, off, 64);
  return v;
}
__device__ __forceinline__ float gelu_exact(float x) {
  return 0.5f * x * (1.0f + erff(x * 0.70710678118654752f));
}

// ---------------- input embed: u_aug @ W_in + b + pos_enc ----------------
__global__ __launch_bounds__(256) void embed_kernel(
    const float* __restrict__ u, const float* __restrict__ y,
    const float* __restrict__ W_in, const float* __restrict__ b_in,
    float* __restrict__ X) {
  const int row = blockIdx.x;          // b*T + t
  const int b = row >> 11;             // T = 2048
  const int t = row & 2047;
  const int tid = threadIdx.x;
  __shared__ float ua[24];
  if (tid < 8)       ua[tid] = u[((b << 3) + tid) * TT + t];
  else if (tid < 16) ua[tid] = 0.0f;   // y_aug (phy rollout) is zeros
  else if (tid < 24) ua[tid] = (t < 30) ? y[((b << 3) + (tid - 16)) * TT + t] : 0.0f;
  __syncthreads();
#pragma unroll
  for (int c0 = 0; c0 < 2; ++c0) {
    const int c = c0 * 256 + tid;
    float s = b_in[c];
#pragma unroll
    for (int k = 0; k < 24; ++k) s += ua[k] * W_in[k * HDIM + c];
    const float dv = expf(-0.0179889460337f * (float)(c & ~1));
    const float arg = (float)t * dv;
    s += (c & 1) ? cosf(arg) : sinf(arg);
    X[(size_t)row * HDIM + c] = s;
  }
}

// ---------------- fp32 tiled GEMM: C[M,N] = A[M,K] @ B[K,N] + bias, optional GELU ----------------
template <int ACT>
__global__ __launch_bounds__(256) void gemm_bias(
    const float* __restrict__ A, const float* __restrict__ B,
    const float* __restrict__ bias, float* __restrict__ C,
    int M, int N, int K) {
  __shared__ float As[16][132];
  __shared__ float Bs[16][64];
  const int bm = blockIdx.y * 128;
  const int bn = blockIdx.x * 64;
  const int tid = threadIdx.x;
  const int tx = tid & 15, ty = tid >> 4;
  float acc[8][4] = {};
  for (int k0 = 0; k0 < K; k0 += 16) {
#pragma unroll
    for (int i = 0; i < 8; ++i) {
      const int idx = i * 256 + tid;
      const int m = idx >> 4, k = idx & 15;
      As[k][m] = A[(size_t)(bm + m) * K + k0 + k];
    }
#pragma unroll
    for (int i = 0; i < 4; ++i) {
      const int idx = i * 256 + tid;
      const int k = idx >> 6, n = idx & 63;
      Bs[k][n] = (bn + n < N) ? B[(size_t)(k0 + k) * N + bn + n] : 0.0f;
    }
    __syncthreads();
#pragma unroll
    for (int kk = 0; kk < 16; ++kk) {
      float a[8], bb[4];
#pragma unroll
      for (int i = 0; i < 8; ++i) a[i] = As[kk][ty * 8 + i];
#pragma unroll
      for (int j = 0; j < 4; ++j) bb[j] = Bs[kk][tx * 4 + j];
#pragma unroll
      for (int i = 0; i < 8; ++i)
#pragma unroll
        for (int j = 0; j < 4; ++j) acc[i][j] += a[i] * bb[j];
    }
    __syncthreads();
  }
#pragma unroll
  for (int i = 0; i < 8; ++i) {
    const int m = bm + ty * 8 + i;
#pragma unroll
    for (int j = 0; j < 4; ++j) {
      const int n = bn + tx * 4 + j;
      if (n < N) {
        float v = acc[i][j] + bias[n];
        if (ACT == 1) v = gelu_exact(v);
        C[(size_t)m * N + n] = v;
      }
    }
  }
}

// ---------------- flash-style sliding-window attention ----------------
// One block = (b, head, 32-query tile). K/V staged in 32-key LDS tiles.
// qkv row layout: [q(512) | k(512) | v(512)]; head hh at [hh*128, hh*128+128).
__global__ __launch_bounds__(256) void attn_flash(
    const float* __restrict__ qkv, float* __restrict__ out) {
  const int q0 = blockIdx.x * 32;
  const int hh = blockIdx.y, b = blockIdx.z;
  const int tid = threadIdx.x;
  __shared__ __align__(16) float Qs[32][132];
  __shared__ __align__(16) float Ks[32][132];
  __shared__ __align__(16) float Vs[32][132];
  __shared__ float Ss[32][36];
  __shared__ float scale_s[32];
  __shared__ float linv_s[32];

  const int c4 = (tid & 31) * 4;       // col (floats) for staging, 32 lanes/row
  const int r8 = tid >> 5;             // staging row base (0..7), rows r8 + 8*i
  const float qscale = 0.08838834764831845f;  // 1/sqrt(128)

  // ---- load Q tile (scaled) ----
#pragma unroll
  for (int i = 0; i < 4; ++i) {
    const int r = r8 + i * 8;
    float4 v = *(const float4*)(qkv + (size_t)(b * TT + q0 + r) * 1536 + hh * 128 + c4);
    v.x *= qscale; v.y *= qscale; v.z *= qscale; v.w *= qscale;
    *(float4*)&Qs[r][c4] = v;
  }

  // per-thread state
  const int tq = tid >> 4, tk = tid & 15;          // score micro-tile coords
  const int pr = tid >> 3, pcg = tid & 7;          // PV row / col-group
  float o[16];
#pragma unroll
  for (int i = 0; i < 16; ++i) o[i] = 0.0f;
  float m_reg = -1e30f, l_reg = 0.0f;              // valid in tid<32 only

  int lo = q0 - (WINDOW - 1); if (lo < 0) lo = 0;
  const int k_first = lo & ~31;

  for (int k0 = k_first; k0 <= q0; k0 += 32) {
    // ---- stage K tile ----
#pragma unroll
    for (int i = 0; i < 4; ++i) {
      const int r = r8 + i * 8;
      float4 v = *(const float4*)(qkv + (size_t)(b * TT + k0 + r) * 1536 + 512 + hh * 128 + c4);
      *(float4*)&Ks[r][c4] = v;
    }
    __syncthreads();

    // ---- scores: rows (tq, tq+16) x cols (tk, tk+16) ----
    float a00 = 0.f, a01 = 0.f, a10 = 0.f, a11 = 0.f;
#pragma unroll
    for (int d = 0; d < 128; d += 4) {
      const float4 qa = *(const float4*)&Qs[tq][d];
      const float4 qb = *(const float4*)&Qs[tq + 16][d];
      const float4 ka = *(const float4*)&Ks[tk][d];
      const float4 kb = *(const float4*)&Ks[tk + 16][d];
      a00 += qa.x * ka.x + qa.y * ka.y + qa.z * ka.z + qa.w * ka.w;
      a01 += qa.x * kb.x + qa.y * kb.y + qa.z * kb.z + qa.w * kb.w;
      a10 += qb.x * ka.x + qb.y * ka.y + qb.z * ka.z + qb.w * ka.w;
      a11 += qb.x * kb.x + qb.y * kb.y + qb.z * kb.z + qb.w * kb.w;
    }
    Ss[tq][tk] = a00;
    Ss[tq][tk + 16] = a01;
    Ss[tq + 16][tk] = a10;
    Ss[tq + 16][tk + 16] = a11;
    __syncthreads();

    // ---- stage V tile (all threads), then row softmax (tid<32) ----
#pragma unroll
    for (int i = 0; i < 4; ++i) {
      const int r = r8 + i * 8;
      float4 v = *(const float4*)(qkv + (size_t)(b * TT + k0 + r) * 1536 + 1024 + hh * 128 + c4);
      *(float4*)&Vs[r][c4] = v;
    }
    if (tid < 32) {
      const int q = tid, qg = q0 + q;
      float mt = -1e30f;
#pragma unroll 8
      for (int j = 0; j < 32; ++j) {
        const int kj = k0 + j;
        if (kj <= qg && kj > qg - WINDOW) mt = fmaxf(mt, Ss[q][j]);
      }
      const float mn = fmaxf(m_reg, mt);
      const float sc = expf(m_reg - mn);
      float s = 0.0f;
#pragma unroll 8
      for (int j = 0; j < 32; ++j) {
        const int kj = k0 + j;
        const bool ok = (kj <= qg) && (kj > qg - WINDOW);
        const float p = ok ? expf(Ss[q][j] - mn) : 0.0f;
        Ss[q][j] = p;
        s += p;
      }
      m_reg = mn;
      l_reg = l_reg * sc + s;
      scale_s[q] = sc;
    }
    __syncthreads();

    // ---- PV: O[pr][pcg*4 + 32k] += P[pr][j] * V[j][...] ----
    const float sc = scale_s[pr];
#pragma unroll
    for (int i = 0; i < 16; ++i) o[i] *= sc;
#pragma unroll 8
    for (int j = 0; j < 32; ++j) {
      const float p = Ss[pr][j];
      const float4 v0 = *(const float4*)&Vs[j][pcg * 4];
      const float4 v1 = *(const float4*)&Vs[j][pcg * 4 + 32];
      const float4 v2 = *(const float4*)&Vs[j][pcg * 4 + 64];
      const float4 v3 = *(const float4*)&Vs[j][pcg * 4 + 96];
      o[0]  += p * v0.x; o[1]  += p * v0.y; o[2]  += p * v0.z; o[3]  += p * v0.w;
      o[4]  += p * v1.x; o[5]  += p * v1.y; o[6]  += p * v1.z; o[7]  += p * v1.w;
      o[8]  += p * v2.x; o[9]  += p * v2.y; o[10] += p * v2.z; o[11] += p * v2.w;
      o[12] += p * v3.x; o[13] += p * v3.y; o[14] += p * v3.z; o[15] += p * v3.w;
    }
    __syncthreads();
  }

  if (tid < 32) linv_s[tid] = 1.0f / l_reg;
  __syncthreads();
  const float li = linv_s[pr];
  float* dst = out + (size_t)(b * TT + q0 + pr) * HDIM + hh * 128 + pcg * 4;
#pragma unroll
  for (int k = 0; k < 4; ++k) {
    float4 v;
    v.x = o[k * 4 + 0] * li; v.y = o[k * 4 + 1] * li;
    v.z = o[k * 4 + 2] * li; v.w = o[k * 4 + 3] * li;
    *(float4*)(dst + 32 * k) = v;
  }
}

// ---------------- residual + LayerNorm ----------------
template <int HAS_RES>
__global__ __launch_bounds__(128) void ln_kernel(
    const float* __restrict__ x, const float* __restrict__ r,
    const float* __restrict__ g, const float* __restrict__ be,
    float* __restrict__ out) {
  const int row = blockIdx.x, tid = threadIdx.x;
  float4 v = ((const float4*)(x + (size_t)row * HDIM))[tid];
  if (HAS_RES) {
    const float4 rv = ((const float4*)(r + (size_t)row * HDIM))[tid];
    v.x += rv.x; v.y += rv.y; v.z += rv.z; v.w += rv.w;
  }
  __shared__ float red[2];
  float s = v.x + v.y + v.z + v.w;
  s = wred_sum(s);
  if ((tid & 63) == 0) red[tid >> 6] = s;
  __syncthreads();
  const float mean = (red[0] + red[1]) * (1.0f / 512.0f);
  const float dx = v.x - mean, dy = v.y - mean, dz = v.z - mean, dw = v.w - mean;
  float s2 = dx * dx + dy * dy + dz * dz + dw * dw;
  __syncthreads();
  s2 = wred_sum(s2);
  if ((tid & 63) == 0) red[tid >> 6] = s2;
  __syncthreads();
  const float var = (red[0] + red[1]) * (1.0f / 512.0f);
  const float inv = 1.0f / sqrtf(var + 1e-5f);
  const float4 gv = ((const float4*)g)[tid];
  const float4 bv = ((const float4*)be)[tid];
  float4 o;
  o.x = dx * inv * gv.x + bv.x;
  o.y = dy * inv * gv.y + bv.y;
  o.z = dz * inv * gv.z + bv.z;
  o.w = dw * inv * gv.w + bv.w;
  ((float4*)(out + (size_t)row * HDIM))[tid] = o;
}

// ---------------- fused me3 projection + SSE loss partials ----------------
__global__ __launch_bounds__(256) void head_loss_kernel(
    const float* __restrict__ hme, const float* __restrict__ w3,
    const float* __restrict__ b3, const float* __restrict__ y,
    float* __restrict__ partials) {
  const int row = blockIdx.x;
  const int b = row >> 11, t = row & 2047;
  const int tid = threadIdx.x;
  __shared__ __align__(16) float hl[512];
  __shared__ float acc8[8];
  ((float2*)hl)[tid] = ((const float2*)(hme + (size_t)row * HDIM))[tid];
  __syncthreads();
  const int d = tid >> 5, l32 = tid & 31;
  float s = 0.0f;
  for (int k = l32; k < 512; k += 32) s += hl[k] * w3[k * 8 + d];
#pragma unroll
  for (int off = 16; off; off >>= 1) s += __shfl_xor(s, off, 64);
  if (l32 == 0) {
    const float yh = s + b3[d];
    const float diff = yh - y[((b << 3) + d) * TT + t];
    acc8[d] = diff * diff;
  }
  __syncthreads();
  if (tid == 0) {
    float tot = 0.0f;
#pragma unroll
    for (int i = 0; i < 8; ++i) tot += acc8[i];
    partials[row] = tot;
  }
}

__global__ __launch_bounds__(256) void reduce_kernel(
    const float* __restrict__ partials, float* __restrict__ out, int n) {
  float s = 0.0f;
  for (int i = threadIdx.x; i < n; i += 256) s += partials[i];
  s = wred_sum(s);
  __shared__ float red[4];
  if ((threadIdx.x & 63) == 0) red[threadIdx.x >> 6] = s;
  __syncthreads();
  if (threadIdx.x == 0) out[0] = red[0] + red[1] + red[2] + red[3];
}

// ---------------- host ----------------
extern "C" void kernel_launch(void* const* d_in, const int* in_sizes, int n_in,
                              void* d_out, int out_size, void* d_ws, size_t ws_size,
                              hipStream_t stream) {
  (void)in_sizes; (void)n_in; (void)out_size; (void)ws_size;
  const float* u     = (const float*)d_in[0];
  const float* y     = (const float*)d_in[1];
  const float* W_in  = (const float*)d_in[2];
  const float* b_in  = (const float*)d_in[3];
  const float* qkv_w = (const float*)d_in[4];
  const float* qkv_b = (const float*)d_in[5];
  const float* out_w = (const float*)d_in[6];
  const float* out_b = (const float*)d_in[7];
  const float* ff1_w = (const float*)d_in[8];
  const float* ff1_b = (const float*)d_in[9];
  const float* ff2_w = (const float*)d_in[10];
  const float* ff2_b = (const float*)d_in[11];
  const float* ln1_g = (const float*)d_in[12];
  const float* ln1_b = (const float*)d_in[13];
  const float* ln2_g = (const float*)d_in[14];
  const float* ln2_b = (const float*)d_in[15];
  const float* lnf_g = (const float*)d_in[16];
  const float* lnf_b = (const float*)d_in[17];
  const float* xm1_w = (const float*)d_in[18];
  const float* xm1_b = (const float*)d_in[19];
  const float* xm2_w = (const float*)d_in[20];
  const float* xm2_b = (const float*)d_in[21];
  const float* me1_w = (const float*)d_in[22];
  const float* me1_b = (const float*)d_in[23];
  const float* me2_w = (const float*)d_in[24];
  const float* me2_b = (const float*)d_in[25];
  const float* me3_w = (const float*)d_in[26];
  const float* me3_b = (const float*)d_in[27];

  const int M = BB * TT;  // 8192
  char* ws = (char*)d_ws;
  float* X    = (float*)(ws);                         // 16 MB [8192,512]
  float* QKV  = (float*)(ws + (size_t)(16u << 20));   // 48 MB [8192,1536]
  float* ATT  = (float*)(ws + (size_t)(64u << 20));   // 16 MB [8192,512]
  float* PRJ  = (float*)(ws + (size_t)(80u << 20));   // 16 MB [8192,512]
  float* FF   = (float*)(ws + (size_t)(96u << 20));   // 64 MB [8192,2048]
  float* XM   = (float*)(ws + (size_t)(160u << 20));  // 512 KB [8192,16]
  float* PART = (float*)(ws + (size_t)(161u << 20));  // 32 KB [8192]

  embed_kernel<<<M, 256, 0, stream>>>(u, y, W_in, b_in, X);

  for (int l = 0; l < LAYERS; ++l) {
    gemm_bias<0><<<dim3(1536 / 64, M / 128), 256, 0, stream>>>(
        X, qkv_w + (size_t)l * 512 * 1536, qkv_b + l * 1536, QKV, M, 1536, 512);
    attn_flash<<<dim3(TT / 32, NH, BB), 256, 0, stream>>>(QKV, ATT);
    gemm_bias<0><<<dim3(512 / 64, M / 128), 256, 0, stream>>>(
        ATT, out_w + (size_t)l * 512 * 512, out_b + l * 512, PRJ, M, 512, 512);
    ln_kernel<1><<<M, 128, 0, stream>>>(X, PRJ, ln1_g + l * 512, ln1_b + l * 512, X);
    gemm_bias<1><<<dim3(2048 / 64, M / 128), 256, 0, stream>>>(
        X, ff1_w + (size_t)l * 512 * 2048, ff1_b + l * 2048, FF, M, 2048, 512);
    gemm_bias<0><<<dim3(512 / 64, M / 128), 256, 0, stream>>>(
        FF, ff2_w + (size_t)l * 2048 * 512, ff2_b + l * 512, PRJ, M, 512, 2048);
    ln_kernel<1><<<M, 128, 0, stream>>>(X, PRJ, ln2_g + l * 512, ln2_b + l * 512, X);
  }
  ln_kernel<0><<<M, 128, 0, stream>>>(X, nullptr, lnf_g, lnf_b, X);

  gemm_bias<1><<<dim3(8, 64), 256, 0, stream>>>(X, xm1_w, xm1_b, PRJ, M, 512, 512);
  gemm_bias<0><<<dim3(1, 64), 256, 0, stream>>>(PRJ, xm2_w, xm2_b, XM, M, 16, 512);
  gemm_bias<1><<<dim3(8, 64), 256, 0, stream>>>(XM, me1_w, me1_b, ATT, M, 512, 16);
  gemm_bias<1><<<dim3(8, 64), 256, 0, stream>>>(ATT, me2_w, me2_b, PRJ, M, 512, 512);
  head_loss_kernel<<<M, 256, 0, stream>>>(PRJ, me3_w, me3_b, y, PART);
  reduce_kernel<<<1, 256, 0, stream>>>(PART, (float*)d_out, M);
}

// Round 3
// 3050.878 us; speedup vs baseline: 8.6068x; 2.1510x over previous
//
#include <hip/hip_runtime.h>
#include <cstdint>
#include <cstddef>

#define TT 2048
#define BB 4
#define HDIM 512
#define NH 4
#define LAYERS 4
#define WINDOW 606

typedef __attribute__((ext_vector_type(8))) short bf16x8s;
typedef __attribute__((ext_vector_type(4))) float f32x4;

// ---------------- helpers ----------------
__device__ __forceinline__ float wred_sum(float v) {
#pragma unroll
  for (int off = 32; off; off >>= 1) v += __shfl_xor(v, off, 64);
  return v;
}
__device__ __forceinline__ float gelu_exact(float x) {
  return 0.5f * x * (1.0f + erff(x * 0.70710678118654752f));
}
__device__ __forceinline__ ushort bf16_rne(float v) {
  uint32_t u = __float_as_uint(v);
  u += 0x7FFFu + ((u >> 16) & 1u);
  return (ushort)(u >> 16);
}
__device__ __forceinline__ void split3(float v, ushort& h, ushort& l) {
  h = bf16_rne(v);
  const float hf = __uint_as_float(((uint32_t)h) << 16);
  l = bf16_rne(v - hf);
}
__device__ __forceinline__ void gld_lds16(const void* g, void* l) {
  __builtin_amdgcn_global_load_lds(
      (const __attribute__((address_space(1))) uint32_t*)g,
      (__attribute__((address_space(3))) uint32_t*)l, 16, 0, 0);
}

// ---------------- input embed: u_aug @ W_in + b + pos_enc (f32 out + bf16x3 pack) ----------------
__global__ __launch_bounds__(256) void embed_kernel(
    const float* __restrict__ u, const float* __restrict__ y,
    const float* __restrict__ W_in, const float* __restrict__ b_in,
    float* __restrict__ X, ushort* __restrict__ xp) {
  const int row = blockIdx.x;
  const int b = row >> 11;
  const int t = row & 2047;
  const int tid = threadIdx.x;
  __shared__ float ua[24];
  if (tid < 8)       ua[tid] = u[((b << 3) + tid) * TT + t];
  else if (tid < 16) ua[tid] = 0.0f;   // y_aug (phy rollout) is zeros
  else if (tid < 24) ua[tid] = (t < 30) ? y[((b << 3) + (tid - 16)) * TT + t] : 0.0f;
  __syncthreads();
#pragma unroll
  for (int c0 = 0; c0 < 2; ++c0) {
    const int c = c0 * 256 + tid;
    float s = b_in[c];
#pragma unroll
    for (int k = 0; k < 24; ++k) s += ua[k] * W_in[k * HDIM + c];
    const float dv = expf(-0.0179889460337f * (float)(c & ~1));
    const float arg = (float)t * dv;
    s += (c & 1) ? cosf(arg) : sinf(arg);
    X[(size_t)row * HDIM + c] = s;
    ushort h, l2; split3(s, h, l2);
    xp[(size_t)row * 1536 + c] = h;
    xp[(size_t)row * 1536 + 512 + c] = l2;
    xp[(size_t)row * 1536 + 1024 + c] = h;
  }
}

// ---------------- weight pack: W[K][N] f32 -> Wp[N][3K] bf16 = [hi | hi | lo] ----------------
__global__ __launch_bounds__(256) void packB_kernel(
    const float* __restrict__ W, ushort* __restrict__ Wp, int K, int N) {
  __shared__ float tile[32][33];
  const int tid = threadIdx.x;
  const int bk = blockIdx.x * 32, bn = blockIdx.y * 32;
  const int i0 = tid >> 5, j = tid & 31;
#pragma unroll
  for (int i = 0; i < 4; ++i) {
    const int kk = i0 + i * 8;
    tile[kk][j] = W[(size_t)(bk + kk) * N + bn + j];
  }
  __syncthreads();
#pragma unroll
  for (int i = 0; i < 4; ++i) {
    const int nn = i0 + i * 8;
    const float v = tile[j][nn];
    ushort h, l2; split3(v, h, l2);
    ushort* base = Wp + (size_t)(bn + nn) * (3 * K) + bk + j;
    base[0] = h; base[K] = h; base[2 * K] = l2;
  }
}

// ---------------- bf16 MFMA GEMM: C[M,N] = Ap[M,K3] * Bp[N,K3]^T (+bias, opt GELU, opt pack) ----------------
// Ap = [hi|lo|hi] pack of A[M,K]; Bp = [hi|hi|lo] pack of B[K,N] transposed. K3 = 3K.
// 128x128 tile, BK=32, 4 waves, 16x16x32 MFMA. M%128==0, N%128==0, K3%32==0.
template <int ACT, int PACK>
__global__ __launch_bounds__(256) void gemm_mfma(
    const ushort* __restrict__ Ap, const ushort* __restrict__ Bp,
    const float* __restrict__ bias, float* __restrict__ C,
    ushort* __restrict__ Cp, int M, int N, int K3) {
  __shared__ ushort Als[4096];   // [128][32]
  __shared__ ushort Bls[4096];   // [128][32]
  __shared__ float biasL[128];
  const int tid = threadIdx.x;
  const int bn = blockIdx.x * 128, bm = blockIdx.y * 128;
  const int w = tid >> 6, ln = tid & 63;
  const int wr = (w >> 1) * 64, wc = (w & 1) * 64;
  const int c = ln & 15, g = ln >> 4;
  if (tid < 128) biasL[tid] = bias[bn + tid];

  const int off0 = (w << 11) + (ln << 4);
  const int off1 = off0 + 1024;
  const int row0 = off0 >> 6, ch0 = (off0 >> 4) & 3;
  const int row1 = off1 >> 6, ch1 = (off1 >> 4) & 3;
  const ushort* a0 = Ap + (size_t)(bm + row0) * K3 + ch0 * 8;
  const ushort* a1 = Ap + (size_t)(bm + row1) * K3 + ch1 * 8;
  const ushort* b0 = Bp + (size_t)(bn + row0) * K3 + ch0 * 8;
  const ushort* b1 = Bp + (size_t)(bn + row1) * K3 + ch1 * 8;
  char* lA0 = (char*)Als + off0; char* lA1 = (char*)Als + off1;
  char* lB0 = (char*)Bls + off0; char* lB1 = (char*)Bls + off1;

  f32x4 acc[4][4] = {};
  const int nk = K3 >> 5;
  for (int kt = 0; kt < nk; ++kt) {
    const int k0 = kt << 5;
    gld_lds16(a0 + k0, lA0);
    gld_lds16(a1 + k0, lA1);
    gld_lds16(b0 + k0, lB0);
    gld_lds16(b1 + k0, lB1);
    __syncthreads();
    bf16x8s fa[4], fb[4];
#pragma unroll
    for (int i = 0; i < 4; ++i)
      fa[i] = *(const bf16x8s*)&Als[(wr + i * 16 + c) * 32 + g * 8];
#pragma unroll
    for (int i = 0; i < 4; ++i)
      fb[i] = *(const bf16x8s*)&Bls[(wc + i * 16 + c) * 32 + g * 8];
#pragma unroll
    for (int i = 0; i < 4; ++i)
#pragma unroll
      for (int j = 0; j < 4; ++j)
        acc[i][j] = __builtin_amdgcn_mfma_f32_16x16x32_bf16(fa[i], fb[j], acc[i][j], 0, 0, 0);
    __syncthreads();
  }
  // epilogue: C/D layout col=lane&15, row=(lane>>4)*4+reg  [m89-verified]
#pragma unroll
  for (int i = 0; i < 4; ++i) {
    const int grow0 = bm + wr + i * 16 + g * 4;
#pragma unroll
    for (int j = 0; j < 4; ++j) {
      const int gcol = bn + wc + j * 16 + c;
      const float bv = biasL[wc + j * 16 + c];
#pragma unroll
      for (int r = 0; r < 4; ++r) {
        float v = acc[i][j][r] + bv;
        if (ACT) v = gelu_exact(v);
        if (PACK) {
          ushort h, l2; split3(v, h, l2);
          ushort* base = Cp + (size_t)(grow0 + r) * (3 * N) + gcol;
          base[0] = h; base[N] = l2; base[2 * N] = h;
        } else {
          C[(size_t)(grow0 + r) * N + gcol] = v;
        }
      }
    }
  }
}

// ---------------- fp32 tiled GEMM (small shapes: xm2, me1) ----------------
template <int ACT, int PACK>
__global__ __launch_bounds__(256) void gemm_bias(
    const float* __restrict__ A, const float* __restrict__ B,
    const float* __restrict__ bias, float* __restrict__ C,
    ushort* __restrict__ Cp, int M, int N, int K) {
  __shared__ float As[16][132];
  __shared__ float Bs[16][64];
  const int bm = blockIdx.y * 128;
  const int bn = blockIdx.x * 64;
  const int tid = threadIdx.x;
  const int tx = tid & 15, ty = tid >> 4;
  float acc[8][4] = {};
  for (int k0 = 0; k0 < K; k0 += 16) {
#pragma unroll
    for (int i = 0; i < 8; ++i) {
      const int idx = i * 256 + tid;
      const int m = idx >> 4, k = idx & 15;
      As[k][m] = A[(size_t)(bm + m) * K + k0 + k];
    }
#pragma unroll
    for (int i = 0; i < 4; ++i) {
      const int idx = i * 256 + tid;
      const int k = idx >> 6, n = idx & 63;
      Bs[k][n] = (bn + n < N) ? B[(size_t)(k0 + k) * N + bn + n] : 0.0f;
    }
    __syncthreads();
#pragma unroll
    for (int kk = 0; kk < 16; ++kk) {
      float a[8], bb[4];
#pragma unroll
      for (int i = 0; i < 8; ++i) a[i] = As[kk][ty * 8 + i];
#pragma unroll
      for (int j = 0; j < 4; ++j) bb[j] = Bs[kk][tx * 4 + j];
#pragma unroll
      for (int i = 0; i < 8; ++i)
#pragma unroll
        for (int j = 0; j < 4; ++j) acc[i][j] += a[i] * bb[j];
    }
    __syncthreads();
  }
#pragma unroll
  for (int i = 0; i < 8; ++i) {
    const int m = bm + ty * 8 + i;
#pragma unroll
    for (int j = 0; j < 4; ++j) {
      const int n = bn + tx * 4 + j;
      if (n < N) {
        float v = acc[i][j] + bias[n];
        if (ACT) v = gelu_exact(v);
        if (PACK) {
          ushort h, l2; split3(v, h, l2);
          ushort* base = Cp + (size_t)m * (3 * N) + n;
          base[0] = h; base[N] = l2; base[2 * N] = h;
        } else {
          C[(size_t)m * N + n] = v;
        }
      }
    }
  }
}

// ---------------- flash sliding-window attention, wave-parallel softmax, pack epilogue ----------------
__global__ __launch_bounds__(256) void attn_flash(
    const float* __restrict__ qkv, ushort* __restrict__ atp) {
  const int q0 = blockIdx.x * 32;
  const int hh = blockIdx.y, b = blockIdx.z;
  const int tid = threadIdx.x;
  __shared__ __align__(16) float Qs[32][132];
  __shared__ __align__(16) float Ks[32][132];
  __shared__ __align__(16) float Vs[32][132];
  __shared__ float Ss[32][33];
  __shared__ float rowmax[32];
  __shared__ float psum[32][9];
  __shared__ float mrow[2][32], lrow[2][32];

  const int c4 = (tid & 31) * 4;
  const int r8 = tid >> 5;
  const float qscale = 0.08838834764831845f;  // 1/sqrt(128)

#pragma unroll
  for (int i = 0; i < 4; ++i) {
    const int r = r8 + i * 8;
    float4 v = *(const float4*)(qkv + (size_t)(b * TT + q0 + r) * 1536 + hh * 128 + c4);
    v.x *= qscale; v.y *= qscale; v.z *= qscale; v.w *= qscale;
    *(float4*)&Qs[r][c4] = v;
  }
  if (tid < 32) { mrow[0][tid] = -1e30f; lrow[0][tid] = 0.0f; }
  int par = 0;

  const int tq = tid >> 4, tk = tid & 15;
  const int pr = tid >> 3, pcg = tid & 7;
  const int sq = tid & 31, sg = tid >> 5;
  const int qg_a = q0 + tq, qg_b = q0 + tq + 16;
  float o[16];
#pragma unroll
  for (int i = 0; i < 16; ++i) o[i] = 0.0f;

  int lo_ = q0 - (WINDOW - 1); if (lo_ < 0) lo_ = 0;
  const int k_first = lo_ & ~31;

  for (int k0 = k_first; k0 <= q0; k0 += 32) {
    // stage K
#pragma unroll
    for (int i = 0; i < 4; ++i) {
      const int r = r8 + i * 8;
      *(float4*)&Ks[r][c4] =
          *(const float4*)(qkv + (size_t)(b * TT + k0 + r) * 1536 + 512 + hh * 128 + c4);
    }
    __syncthreads();  // (1)

    // scores + mask + shfl row-max
    float a00 = 0.f, a01 = 0.f, a10 = 0.f, a11 = 0.f;
#pragma unroll
    for (int d = 0; d < 128; d += 4) {
      const float4 qa = *(const float4*)&Qs[tq][d];
      const float4 qb = *(const float4*)&Qs[tq + 16][d];
      const float4 ka = *(const float4*)&Ks[tk][d];
      const float4 kb = *(const float4*)&Ks[tk + 16][d];
      a00 += qa.x * ka.x + qa.y * ka.y + qa.z * ka.z + qa.w * ka.w;
      a01 += qa.x * kb.x + qa.y * kb.y + qa.z * kb.z + qa.w * kb.w;
      a10 += qb.x * ka.x + qb.y * ka.y + qb.z * ka.z + qb.w * ka.w;
      a11 += qb.x * kb.x + qb.y * kb.y + qb.z * kb.z + qb.w * kb.w;
    }
    const int kja = k0 + tk, kjb = k0 + tk + 16;
    a00 = (kja <= qg_a && kja > qg_a - WINDOW) ? a00 : -1e30f;
    a01 = (kjb <= qg_a && kjb > qg_a - WINDOW) ? a01 : -1e30f;
    a10 = (kja <= qg_b && kja > qg_b - WINDOW) ? a10 : -1e30f;
    a11 = (kjb <= qg_b && kjb > qg_b - WINDOW) ? a11 : -1e30f;
    Ss[tq][tk] = a00; Ss[tq][tk + 16] = a01;
    Ss[tq + 16][tk] = a10; Ss[tq + 16][tk + 16] = a11;
    float mlo = fmaxf(a00, a01), mhi = fmaxf(a10, a11);
#pragma unroll
    for (int off = 1; off < 16; off <<= 1) {
      mlo = fmaxf(mlo, __shfl_xor(mlo, off, 16));
      mhi = fmaxf(mhi, __shfl_xor(mhi, off, 16));
    }
    if (tk == 0) { rowmax[tq] = mlo; rowmax[tq + 16] = mhi; }
    __syncthreads();  // (2)

    // stage V
#pragma unroll
    for (int i = 0; i < 4; ++i) {
      const int r = r8 + i * 8;
      *(float4*)&Vs[r][c4] =
          *(const float4*)(qkv + (size_t)(b * TT + k0 + r) * 1536 + 1024 + hh * 128 + c4);
    }
    // exp phase (all 256 threads; 4 cols each)
    {
      const float mn_s = fmaxf(mrow[par][sq], rowmax[sq]);
      float ps = 0.0f;
#pragma unroll
      for (int jj = 0; jj < 4; ++jj) {
        const int jx = sg * 4 + jj;
        const float s = Ss[sq][jx];
        const float p = (s > -1e29f) ? expf(s - mn_s) : 0.0f;
        Ss[sq][jx] = p;
        ps += p;
      }
      psum[sq][sg] = ps;
    }
    __syncthreads();  // (3)

    // state update (for next tile) into par^1
    if (tid < 32) {
      float s8 = 0.0f;
#pragma unroll
      for (int gg = 0; gg < 8; ++gg) s8 += psum[tid][gg];
      const float mo = mrow[par][tid];
      const float mn = fmaxf(mo, rowmax[tid]);
      mrow[par ^ 1][tid] = mn;
      lrow[par ^ 1][tid] = lrow[par][tid] * expf(mo - mn) + s8;
    }
    // PV (reads par-buffer state; concurrent with tid<32 writing par^1)
    {
      const float mo = mrow[par][pr];
      const float mn = fmaxf(mo, rowmax[pr]);
      const float sc = expf(mo - mn);
#pragma unroll
      for (int i = 0; i < 16; ++i) o[i] *= sc;
#pragma unroll 8
      for (int j = 0; j < 32; ++j) {
        const float p = Ss[pr][j];
        const float4 v0 = *(const float4*)&Vs[j][pcg * 4];
        const float4 v1 = *(const float4*)&Vs[j][pcg * 4 + 32];
        const float4 v2 = *(const float4*)&Vs[j][pcg * 4 + 64];
        const float4 v3 = *(const float4*)&Vs[j][pcg * 4 + 96];
        o[0]  += p * v0.x; o[1]  += p * v0.y; o[2]  += p * v0.z; o[3]  += p * v0.w;
        o[4]  += p * v1.x; o[5]  += p * v1.y; o[6]  += p * v1.z; o[7]  += p * v1.w;
        o[8]  += p * v2.x; o[9]  += p * v2.y; o[10] += p * v2.z; o[11] += p * v2.w;
        o[12] += p * v3.x; o[13] += p * v3.y; o[14] += p * v3.z; o[15] += p * v3.w;
      }
    }
    __syncthreads();  // (4)
    par ^= 1;
  }

  const float li = 1.0f / lrow[par][pr];
  ushort* dst = atp + (size_t)(b * TT + q0 + pr) * 1536 + hh * 128 + pcg * 4;
#pragma unroll
  for (int k = 0; k < 4; ++k) {
    ushort4 h4, l4;
    split3(o[k * 4 + 0] * li, h4.x, l4.x);
    split3(o[k * 4 + 1] * li, h4.y, l4.y);
    split3(o[k * 4 + 2] * li, h4.z, l4.z);
    split3(o[k * 4 + 3] * li, h4.w, l4.w);
    *(ushort4*)(dst + 32 * k) = h4;
    *(ushort4*)(dst + 512 + 32 * k) = l4;
    *(ushort4*)(dst + 1024 + 32 * k) = h4;
  }
}

// ---------------- residual + LayerNorm (+ bf16x3 pack out) ----------------
template <int HAS_RES>
__global__ __launch_bounds__(128) void ln_kernel(
    const float* __restrict__ x, const float* __restrict__ r,
    const float* __restrict__ g, const float* __restrict__ be,
    float* __restrict__ out, ushort* __restrict__ xp) {
  const int row = blockIdx.x, tid = threadIdx.x;
  float4 v = ((const float4*)(x + (size_t)row * HDIM))[tid];
  if (HAS_RES) {
    const float4 rv = ((const float4*)(r + (size_t)row * HDIM))[tid];
    v.x += rv.x; v.y += rv.y; v.z += rv.z; v.w += rv.w;
  }
  __shared__ float red[2];
  float s = v.x + v.y + v.z + v.w;
  s = wred_sum(s);
  if ((tid & 63) == 0) red[tid >> 6] = s;
  __syncthreads();
  const float mean = (red[0] + red[1]) * (1.0f / 512.0f);
  const float dx = v.x - mean, dy = v.y - mean, dz = v.z - mean, dw = v.w - mean;
  float s2 = dx * dx + dy * dy + dz * dz + dw * dw;
  __syncthreads();
  s2 = wred_sum(s2);
  if ((tid & 63) == 0) red[tid >> 6] = s2;
  __syncthreads();
  const float var = (red[0] + red[1]) * (1.0f / 512.0f);
  const float inv = 1.0f / sqrtf(var + 1e-5f);
  const float4 gv = ((const float4*)g)[tid];
  const float4 bv = ((const float4*)be)[tid];
  float4 o;
  o.x = dx * inv * gv.x + bv.x;
  o.y = dy * inv * gv.y + bv.y;
  o.z = dz * inv * gv.z + bv.z;
  o.w = dw * inv * gv.w + bv.w;
  ((float4*)(out + (size_t)row * HDIM))[tid] = o;
  ushort4 h4, l4;
  split3(o.x, h4.x, l4.x); split3(o.y, h4.y, l4.y);
  split3(o.z, h4.z, l4.z); split3(o.w, h4.w, l4.w);
  ushort* base = xp + (size_t)row * 1536 + tid * 4;
  *(ushort4*)base = h4;
  *(ushort4*)(base + 512) = l4;
  *(ushort4*)(base + 1024) = h4;
}

// ---------------- fused me3 projection + SSE loss partials ----------------
__global__ __launch_bounds__(256) void head_loss_kernel(
    const float* __restrict__ hme, const float* __restrict__ w3,
    const float* __restrict__ b3, const float* __restrict__ y,
    float* __restrict__ partials) {
  const int row = blockIdx.x;
  const int b = row >> 11, t = row & 2047;
  const int tid = threadIdx.x;
  __shared__ __align__(16) float hl[512];
  __shared__ float acc8[8];
  ((float2*)hl)[tid] = ((const float2*)(hme + (size_t)row * HDIM))[tid];
  __syncthreads();
  const int d = tid >> 5, l32 = tid & 31;
  float s = 0.0f;
  for (int k = l32; k < 512; k += 32) s += hl[k] * w3[k * 8 + d];
#pragma unroll
  for (int off = 16; off; off >>= 1) s += __shfl_xor(s, off, 64);
  if (l32 == 0) {
    const float yh = s + b3[d];
    const float diff = yh - y[((b << 3) + d) * TT + t];
    acc8[d] = diff * diff;
  }
  __syncthreads();
  if (tid == 0) {
    float tot = 0.0f;
#pragma unroll
    for (int i = 0; i < 8; ++i) tot += acc8[i];
    partials[row] = tot;
  }
}

__global__ __launch_bounds__(256) void reduce_kernel(
    const float* __restrict__ partials, float* __restrict__ out, int n) {
  float s = 0.0f;
  for (int i = threadIdx.x; i < n; i += 256) s += partials[i];
  s = wred_sum(s);
  __shared__ float red[4];
  if ((threadIdx.x & 63) == 0) red[threadIdx.x >> 6] = s;
  __syncthreads();
  if (threadIdx.x == 0) out[0] = red[0] + red[1] + red[2] + red[3];
}

// ---------------- host ----------------
extern "C" void kernel_launch(void* const* d_in, const int* in_sizes, int n_in,
                              void* d_out, int out_size, void* d_ws, size_t ws_size,
                              hipStream_t stream) {
  (void)in_sizes; (void)n_in; (void)out_size; (void)ws_size;
  const float* u     = (const float*)d_in[0];
  const float* y     = (const float*)d_in[1];
  const float* W_in  = (const float*)d_in[2];
  const float* b_in  = (const float*)d_in[3];
  const float* qkv_w = (const float*)d_in[4];
  const float* qkv_b = (const float*)d_in[5];
  const float* out_w = (const float*)d_in[6];
  const float* out_b = (const float*)d_in[7];
  const float* ff1_w = (const float*)d_in[8];
  const float* ff1_b = (const float*)d_in[9];
  const float* ff2_w = (const float*)d_in[10];
  const float* ff2_b = (const float*)d_in[11];
  const float* ln1_g = (const float*)d_in[12];
  const float* ln1_b = (const float*)d_in[13];
  const float* ln2_g = (const float*)d_in[14];
  const float* ln2_b = (const float*)d_in[15];
  const float* lnf_g = (const float*)d_in[16];
  const float* lnf_b = (const float*)d_in[17];
  const float* xm1_w = (const float*)d_in[18];
  const float* xm1_b = (const float*)d_in[19];
  const float* xm2_w = (const float*)d_in[20];
  const float* xm2_b = (const float*)d_in[21];
  const float* me1_w = (const float*)d_in[22];
  const float* me1_b = (const float*)d_in[23];
  const float* me2_w = (const float*)d_in[24];
  const float* me2_b = (const float*)d_in[25];
  const float* me3_w = (const float*)d_in[26];
  const float* me3_b = (const float*)d_in[27];

  const int M = BB * TT;  // 8192
  char* ws = (char*)d_ws;
  float*  X    = (float*)(ws);                                   // 16 MB [8192,512] f32
  float*  PRJ  = (float*)(ws + ((size_t)16 << 20));              // 16 MB [8192,512] f32
  float*  QKV  = (float*)(ws + ((size_t)32 << 20));              // 48 MB [8192,1536] f32  (in BIG)
  ushort* FFp  = (ushort*)(ws + ((size_t)32 << 20));             // 96 MB [8192,6144] bf16 (in BIG)
  ushort* PK1  = (ushort*)(ws + ((size_t)128 << 20));            // 24 MB [8192,1536] bf16 pack
  ushort* WSCR = (ushort*)(ws + ((size_t)152 << 20));            //  8 MB weight-pack scratch
  float*  XM   = (float*)(ws + ((size_t)160 << 20));             // 512 KB [8192,16]
  float*  PART = (float*)(ws + ((size_t)160 << 20) + (512u << 10));  // 32 KB

  embed_kernel<<<M, 256, 0, stream>>>(u, y, W_in, b_in, X, PK1);

  for (int l = 0; l < LAYERS; ++l) {
    packB_kernel<<<dim3(16, 48), 256, 0, stream>>>(qkv_w + (size_t)l * 512 * 1536, WSCR, 512, 1536);
    gemm_mfma<0, 0><<<dim3(12, 64), 256, 0, stream>>>(PK1, WSCR, qkv_b + l * 1536, QKV, nullptr, M, 1536, 1536);
    attn_flash<<<dim3(TT / 32, NH, BB), 256, 0, stream>>>(QKV, PK1);
    packB_kernel<<<dim3(16, 16), 256, 0, stream>>>(out_w + (size_t)l * 512 * 512, WSCR, 512, 512);
    gemm_mfma<0, 0><<<dim3(4, 64), 256, 0, stream>>>(PK1, WSCR, out_b + l * 512, PRJ, nullptr, M, 512, 1536);
    ln_kernel<1><<<M, 128, 0, stream>>>(X, PRJ, ln1_g + l * 512, ln1_b + l * 512, X, PK1);
    packB_kernel<<<dim3(16, 64), 256, 0, stream>>>(ff1_w + (size_t)l * 512 * 2048, WSCR, 512, 2048);
    gemm_mfma<1, 1><<<dim3(16, 64), 256, 0, stream>>>(PK1, WSCR, ff1_b + l * 2048, nullptr, FFp, M, 2048, 1536);
    packB_kernel<<<dim3(64, 16), 256, 0, stream>>>(ff2_w + (size_t)l * 2048 * 512, WSCR, 2048, 512);
    gemm_mfma<0, 0><<<dim3(4, 64), 256, 0, stream>>>(FFp, WSCR, ff2_b + l * 512, PRJ, nullptr, M, 512, 6144);
    ln_kernel<1><<<M, 128, 0, stream>>>(X, PRJ, ln2_g + l * 512, ln2_b + l * 512, X, PK1);
  }
  ln_kernel<0><<<M, 128, 0, stream>>>(X, nullptr, lnf_g, lnf_b, X, PK1);

  packB_kernel<<<dim3(16, 16), 256, 0, stream>>>(xm1_w, WSCR, 512, 512);
  gemm_mfma<1, 0><<<dim3(4, 64), 256, 0, stream>>>(PK1, WSCR, xm1_b, PRJ, nullptr, M, 512, 1536);
  gemm_bias<0, 0><<<dim3(1, 64), 256, 0, stream>>>(PRJ, xm2_w, xm2_b, XM, nullptr, M, 16, 512);
  gemm_bias<1, 1><<<dim3(8, 64), 256, 0, stream>>>(XM, me1_w, me1_b, nullptr, PK1, M, 512, 16);
  packB_kernel<<<dim3(16, 16), 256, 0, stream>>>(me2_w, WSCR, 512, 512);
  gemm_mfma<1, 0><<<dim3(4, 64), 256, 0, stream>>>(PK1, WSCR, me2_b, PRJ, nullptr, M, 512, 1536);
  head_loss_kernel<<<M, 256, 0, stream>>>(PRJ, me3_w, me3_b, y, PART);
  reduce_kernel<<<1, 256, 0, stream>>>(PART, (float*)d_out, M);
}

// Round 4
// 2375.674 us; speedup vs baseline: 11.0530x; 1.2842x over previous
//
#include <hip/hip_runtime.h>
#include <cstdint>
#include <cstddef>

#define TT 2048
#define BB 4
#define HDIM 512
#define NH 4
#define LAYERS 4
#define WINDOW 606

#define PLANE_QK 4194304ull   // 16*2048*128
#define PLANE_X  4194304ull   // 8192*512
#define PLANE_FF 16777216ull  // 8192*2048

typedef __attribute__((ext_vector_type(8))) short bf16x8s;
typedef __attribute__((ext_vector_type(4))) float f32x4;

// ---------------- helpers ----------------
__device__ __forceinline__ float wred_sum(float v) {
#pragma unroll
  for (int off = 32; off; off >>= 1) v += __shfl_xor(v, off, 64);
  return v;
}
__device__ __forceinline__ float gelu_exact(float x) {
  return 0.5f * x * (1.0f + erff(x * 0.70710678118654752f));
}
__device__ __forceinline__ ushort bf16_rne(float v) {
  uint32_t u = __float_as_uint(v);
  u += 0x7FFFu + ((u >> 16) & 1u);
  return (ushort)(u >> 16);
}
__device__ __forceinline__ void split3(float v, ushort& h, ushort& l) {
  h = bf16_rne(v);
  const float hf = __uint_as_float(((uint32_t)h) << 16);
  l = bf16_rne(v - hf);
}
__device__ __forceinline__ void gld_lds16(const void* g, void* l) {
  __builtin_amdgcn_global_load_lds(
      (const __attribute__((address_space(1))) uint32_t*)g,
      (__attribute__((address_space(3))) uint32_t*)l, 16, 0, 0);
}

// ---------------- input embed: u_aug @ W_in + b + pos_enc (f32 out + 2-plane pack) ----------------
__global__ __launch_bounds__(256) void embed_kernel(
    const float* __restrict__ u, const float* __restrict__ y,
    const float* __restrict__ W_in, const float* __restrict__ b_in,
    float* __restrict__ X, ushort* __restrict__ xp) {
  const int row = blockIdx.x;
  const int b = row >> 11;
  const int t = row & 2047;
  const int tid = threadIdx.x;
  __shared__ float ua[24];
  if (tid < 8)       ua[tid] = u[((b << 3) + tid) * TT + t];
  else if (tid < 16) ua[tid] = 0.0f;   // y_aug (phy rollout) is zeros
  else if (tid < 24) ua[tid] = (t < 30) ? y[((b << 3) + (tid - 16)) * TT + t] : 0.0f;
  __syncthreads();
#pragma unroll
  for (int c0 = 0; c0 < 2; ++c0) {
    const int c = c0 * 256 + tid;
    float s = b_in[c];
#pragma unroll
    for (int k = 0; k < 24; ++k) s += ua[k] * W_in[k * HDIM + c];
    const float dv = expf(-0.0179889460337f * (float)(c & ~1));
    const float arg = (float)t * dv;
    s += (c & 1) ? cosf(arg) : sinf(arg);
    X[(size_t)row * HDIM + c] = s;
    ushort h, l2; split3(s, h, l2);
    xp[(size_t)row * HDIM + c] = h;
    xp[PLANE_X + (size_t)row * HDIM + c] = l2;
  }
}

// ---------------- weight pack: W[K][N] f32 -> planes [N][K] bf16 hi @0, lo @N*K ----------------
__device__ __forceinline__ void pack_tile(float (*tile)[33],
    const float* __restrict__ W, ushort* __restrict__ Wp,
    int K, int N, int bk, int bn, int tid) {
  const int i0 = tid >> 5, j = tid & 31;
#pragma unroll
  for (int i = 0; i < 4; ++i) {
    const int kk = i0 + i * 8;
    tile[kk][j] = W[(size_t)(bk + kk) * N + bn + j];
  }
  __syncthreads();
  const size_t NK = (size_t)N * K;
#pragma unroll
  for (int i = 0; i < 4; ++i) {
    const int nn = i0 + i * 8;
    const float v = tile[j][nn];
    ushort h, l2; split3(v, h, l2);
    ushort* base = Wp + (size_t)(bn + nn) * K + bk + j;
    base[0] = h; base[NK] = l2;
  }
}

__global__ __launch_bounds__(256) void packL_kernel(
    const float* __restrict__ qkvw, const float* __restrict__ outw,
    const float* __restrict__ ff1w, ushort* __restrict__ Wp) {
  __shared__ float tile[32][33];
  int i = blockIdx.x;
  if (i < 768) {
    pack_tile(tile, qkvw, Wp, 512, 1536, (i & 15) * 32, (i >> 4) * 32, threadIdx.x);
  } else if (i < 1024) {
    i -= 768;
    pack_tile(tile, outw, Wp + 1572864, 512, 512, (i & 15) * 32, (i >> 4) * 32, threadIdx.x);
  } else {
    i -= 1024;
    pack_tile(tile, ff1w, Wp + 2097152, 512, 2048, (i & 15) * 32, (i >> 4) * 32, threadIdx.x);
  }
}

__global__ __launch_bounds__(256) void packF_kernel(
    const float* __restrict__ ff2w, ushort* __restrict__ Wp) {
  __shared__ float tile[32][33];
  const int i = blockIdx.x;
  pack_tile(tile, ff2w, Wp, 2048, 512, (i & 63) * 32, (i >> 6) * 32, threadIdx.x);
}

__global__ __launch_bounds__(256) void packH_kernel(
    const float* __restrict__ xm1w, const float* __restrict__ me2w,
    ushort* __restrict__ Wp) {
  __shared__ float tile[32][33];
  int i = blockIdx.x;
  if (i < 256) pack_tile(tile, xm1w, Wp, 512, 512, (i & 15) * 32, (i >> 4) * 32, threadIdx.x);
  else { i -= 256; pack_tile(tile, me2w, Wp + 524288, 512, 512, (i & 15) * 32, (i >> 4) * 32, threadIdx.x); }
}

// ---------------- bf16 MFMA GEMM: C = A * B^T with 3-term hi/lo split ----------------
// A planes [M][K] (Ah, Al), B planes [N][K] (Bh, Bl). terms: Ah*Bh + Al*Bh + Ah*Bl.
// OUTMODE: 0 = f32 C; 1 = 2-plane bf16 pack Cp (+cplane); 2 = QKV special (Wq).
template <int ACT, int OUTMODE>
__global__ __launch_bounds__(256) void gemm_mfma(
    const ushort* __restrict__ Ah, const ushort* __restrict__ Al,
    const ushort* __restrict__ Bh, const ushort* __restrict__ Bl,
    const float* __restrict__ bias,
    float* __restrict__ C, ushort* __restrict__ Cp, size_t cplane,
    ushort* __restrict__ Wq, int M, int N, int K) {
  __shared__ ushort Als[4096];   // [128][32]
  __shared__ ushort Bls[4096];
  __shared__ float biasL[128];
  const int tid = threadIdx.x;
  const int bn = blockIdx.x * 128, bm = blockIdx.y * 128;
  const int w = tid >> 6, ln = tid & 63;
  const int wr = (w >> 1) * 64, wc = (w & 1) * 64;
  const int c = ln & 15, g = ln >> 4;
  if (tid < 128) biasL[tid] = bias[bn + tid];

  const int off0 = (w << 11) + (ln << 4);
  const int off1 = off0 + 1024;
  const int row0 = off0 >> 6, ch0 = (off0 >> 4) & 3;
  const int row1 = off1 >> 6, ch1 = (off1 >> 4) & 3;
  char* lA0 = (char*)Als + off0; char* lA1 = (char*)Als + off1;
  char* lB0 = (char*)Bls + off0; char* lB1 = (char*)Bls + off1;

  f32x4 acc[4][4] = {};
  const int nkt = K >> 5;
#pragma unroll
  for (int term = 0; term < 3; ++term) {
    const ushort* Ag = (term == 1) ? Al : Ah;
    const ushort* Bg = (term == 2) ? Bl : Bh;
    const ushort* a0 = Ag + (size_t)(bm + row0) * K + ch0 * 8;
    const ushort* a1 = Ag + (size_t)(bm + row1) * K + ch1 * 8;
    const ushort* b0 = Bg + (size_t)(bn + row0) * K + ch0 * 8;
    const ushort* b1 = Bg + (size_t)(bn + row1) * K + ch1 * 8;
    for (int kt = 0; kt < nkt; ++kt) {
      const int k0 = kt << 5;
      gld_lds16(a0 + k0, lA0);
      gld_lds16(a1 + k0, lA1);
      gld_lds16(b0 + k0, lB0);
      gld_lds16(b1 + k0, lB1);
      __syncthreads();
      bf16x8s fa[4], fb[4];
#pragma unroll
      for (int i = 0; i < 4; ++i)
        fa[i] = *(const bf16x8s*)&Als[(wr + i * 16 + c) * 32 + g * 8];
#pragma unroll
      for (int i = 0; i < 4; ++i)
        fb[i] = *(const bf16x8s*)&Bls[(wc + i * 16 + c) * 32 + g * 8];
#pragma unroll
      for (int i = 0; i < 4; ++i)
#pragma unroll
        for (int j = 0; j < 4; ++j)
          acc[i][j] = __builtin_amdgcn_mfma_f32_16x16x32_bf16(fa[i], fb[j], acc[i][j], 0, 0, 0);
      __syncthreads();
    }
  }
  // epilogue: C/D layout col=lane&15, row=(lane>>4)*4+reg [m89-verified]
  const float qscale = 0.08838834764831845f;
#pragma unroll
  for (int i = 0; i < 4; ++i) {
    const int grow0 = bm + wr + i * 16 + g * 4;
#pragma unroll
    for (int j = 0; j < 4; ++j) {
      const int gcol = bn + wc + j * 16 + c;
      const float bv = biasL[wc + j * 16 + c];
      if (OUTMODE == 2) {
        const int bq = grow0 >> 11, tl = grow0 & 2047;
        if (bn < 512) {            // Q: scaled, row-major [bh][t][128]
          const int hh = gcol >> 7, d = gcol & 127;
          ushort* dst = Wq + ((size_t)(bq * NH + hh) * TT + tl) * 128 + d;
#pragma unroll
          for (int r = 0; r < 4; ++r) {
            ushort h, l2; split3((acc[i][j][r] + bv) * qscale, h, l2);
            dst[(size_t)r * 128] = h;
            dst[PLANE_QK + (size_t)r * 128] = l2;
          }
        } else if (bn < 1024) {    // K: row-major [bh][t][128]
          const int hh = (gcol - 512) >> 7, d = gcol & 127;
          ushort* dst = Wq + 2 * PLANE_QK + ((size_t)(bq * NH + hh) * TT + tl) * 128 + d;
#pragma unroll
          for (int r = 0; r < 4; ++r) {
            ushort h, l2; split3(acc[i][j][r] + bv, h, l2);
            dst[(size_t)r * 128] = h;
            dst[PLANE_QK + (size_t)r * 128] = l2;
          }
        } else {                   // V: transposed [bh][d][t]
          const int hh = (gcol - 1024) >> 7, d = gcol & 127;
          ushort4 h4, l4;
          split3(acc[i][j][0] + bv, h4.x, l4.x);
          split3(acc[i][j][1] + bv, h4.y, l4.y);
          split3(acc[i][j][2] + bv, h4.z, l4.z);
          split3(acc[i][j][3] + bv, h4.w, l4.w);
          ushort* dst = Wq + 4 * PLANE_QK + ((size_t)(bq * NH + hh) * 128 + d) * TT + tl;
          *(ushort4*)dst = h4;
          *(ushort4*)(dst + PLANE_QK) = l4;
        }
      } else {
#pragma unroll
        for (int r = 0; r < 4; ++r) {
          float v = acc[i][j][r] + bv;
          if (ACT) v = gelu_exact(v);
          if (OUTMODE == 1) {
            ushort h, l2; split3(v, h, l2);
            ushort* base = Cp + (size_t)(grow0 + r) * N + gcol;
            base[0] = h; base[cplane] = l2;
          } else {
            C[(size_t)(grow0 + r) * N + gcol] = v;
          }
        }
      }
    }
  }
}

// ---------------- fp32 tiled GEMM (small shapes: xm2, me1) ----------------
template <int ACT, int PACK>
__global__ __launch_bounds__(256) void gemm_bias(
    const float* __restrict__ A, const float* __restrict__ B,
    const float* __restrict__ bias, float* __restrict__ C,
    ushort* __restrict__ Cp, size_t cplane, int M, int N, int K) {
  __shared__ float As[16][132];
  __shared__ float Bs[16][64];
  const int bm = blockIdx.y * 128;
  const int bn = blockIdx.x * 64;
  const int tid = threadIdx.x;
  const int tx = tid & 15, ty = tid >> 4;
  float acc[8][4] = {};
  for (int k0 = 0; k0 < K; k0 += 16) {
#pragma unroll
    for (int i = 0; i < 8; ++i) {
      const int idx = i * 256 + tid;
      const int m = idx >> 4, k = idx & 15;
      As[k][m] = A[(size_t)(bm + m) * K + k0 + k];
    }
#pragma unroll
    for (int i = 0; i < 4; ++i) {
      const int idx = i * 256 + tid;
      const int k = idx >> 6, n = idx & 63;
      Bs[k][n] = (bn + n < N) ? B[(size_t)(k0 + k) * N + bn + n] : 0.0f;
    }
    __syncthreads();
#pragma unroll
    for (int kk = 0; kk < 16; ++kk) {
      float a[8], bb[4];
#pragma unroll
      for (int i = 0; i < 8; ++i) a[i] = As[kk][ty * 8 + i];
#pragma unroll
      for (int j = 0; j < 4; ++j) bb[j] = Bs[kk][tx * 4 + j];
#pragma unroll
      for (int i = 0; i < 8; ++i)
#pragma unroll
        for (int j = 0; j < 4; ++j) acc[i][j] += a[i] * bb[j];
    }
    __syncthreads();
  }
#pragma unroll
  for (int i = 0; i < 8; ++i) {
    const int m = bm + ty * 8 + i;
#pragma unroll
    for (int j = 0; j < 4; ++j) {
      const int n = bn + tx * 4 + j;
      if (n < N) {
        float v = acc[i][j] + bias[n];
        if (ACT) v = gelu_exact(v);
        if (PACK) {
          ushort h, l2; split3(v, h, l2);
          ushort* base = Cp + (size_t)m * N + n;
          base[0] = h; base[cplane] = l2;
        } else {
          C[(size_t)m * N + n] = v;
        }
      }
    }
  }
}

// ---------------- MFMA flash sliding-window attention, frags direct from L2 ----------------
// QKVp planes: Qh|Ql|Kh|Kl|Vth|Vtl, each PLANE_QK. Q/K: [bh][t][128]; Vt: [bh][d][t].
// Output: 2-plane bf16 pack atp [8192][512] (+PLANE_X lo).
__global__ __launch_bounds__(256) void attn_mfma(
    const ushort* __restrict__ QKVp, ushort* __restrict__ atp) {
  const int q0 = blockIdx.x * 32;
  const int hh = blockIdx.y, b = blockIdx.z;
  const int bh = b * NH + hh;
  const int tid = threadIdx.x;
  const int w = tid >> 6, lane = tid & 63;
  const int c = lane & 15, g = lane >> 4;
  const int wr = w >> 1, wc = w & 1;

  __shared__ ushort Ph[32][40], Pl[32][40];
  __shared__ float wmax[2][32], wsum[2][32];
  __shared__ float mrow[2][32], lrow[2][32];

  const ushort* Qh = QKVp;
  const ushort* Ql = QKVp + PLANE_QK;
  const ushort* Kh = QKVp + 2 * PLANE_QK;
  const ushort* Kl = QKVp + 3 * PLANE_QK;
  const ushort* Vh = QKVp + 4 * PLANE_QK;
  const ushort* Vl = QKVp + 5 * PLANE_QK;

  const size_t qkbase = (size_t)bh * TT * 128;
  const size_t vtbase = (size_t)bh * 128 * TT;

  // Q fragments held in registers for the whole kernel (A rows = q0+wr*16+c)
  bf16x8s qh[4], ql[4];
  {
    const ushort* qr = Qh + qkbase + (size_t)(q0 + wr * 16 + c) * 128 + g * 8;
    const ushort* qr2 = Ql + qkbase + (size_t)(q0 + wr * 16 + c) * 128 + g * 8;
#pragma unroll
    for (int kc = 0; kc < 4; ++kc) {
      qh[kc] = *(const bf16x8s*)(qr + kc * 32);
      ql[kc] = *(const bf16x8s*)(qr2 + kc * 32);
    }
  }

  if (tid < 32) { mrow[0][tid] = -1e30f; lrow[0][tid] = 0.0f; }
  __syncthreads();

  f32x4 oacc[2][2] = {};
  int par = 0;
  int lo_ = q0 - (WINDOW - 1); if (lo_ < 0) lo_ = 0;
  const int k_first = lo_ & ~31;

  for (int k0 = k_first; k0 <= q0; k0 += 32) {
    // V fragments (prefetch; consumed after barrier C)
    const bf16x8s vh0 = *(const bf16x8s*)(Vh + vtbase + (size_t)(w * 32 + c) * TT + k0 + g * 8);
    const bf16x8s vh1 = *(const bf16x8s*)(Vh + vtbase + (size_t)(w * 32 + 16 + c) * TT + k0 + g * 8);
    const bf16x8s vl0 = *(const bf16x8s*)(Vl + vtbase + (size_t)(w * 32 + c) * TT + k0 + g * 8);
    const bf16x8s vl1 = *(const bf16x8s*)(Vl + vtbase + (size_t)(w * 32 + 16 + c) * TT + k0 + g * 8);

    // scores: this wave's 16x16 quadrant (rows wr, cols wc), 3-term split
    f32x4 sacc = {};
    {
      const ushort* kr = Kh + qkbase + (size_t)(k0 + wc * 16 + c) * 128 + g * 8;
      const ushort* kr2 = Kl + qkbase + (size_t)(k0 + wc * 16 + c) * 128 + g * 8;
      bf16x8s kh[4], kl[4];
#pragma unroll
      for (int kc = 0; kc < 4; ++kc) {
        kh[kc] = *(const bf16x8s*)(kr + kc * 32);
        kl[kc] = *(const bf16x8s*)(kr2 + kc * 32);
      }
#pragma unroll
      for (int kc = 0; kc < 4; ++kc)
        sacc = __builtin_amdgcn_mfma_f32_16x16x32_bf16(qh[kc], kh[kc], sacc, 0, 0, 0);
#pragma unroll
      for (int kc = 0; kc < 4; ++kc)
        sacc = __builtin_amdgcn_mfma_f32_16x16x32_bf16(ql[kc], kh[kc], sacc, 0, 0, 0);
#pragma unroll
      for (int kc = 0; kc < 4; ++kc)
        sacc = __builtin_amdgcn_mfma_f32_16x16x32_bf16(qh[kc], kl[kc], sacc, 0, 0, 0);
    }
    // mask + per-row tile max (reduce over 16 col-lanes)
    const int jcol = k0 + wc * 16 + c;
    float s[4], mx[4];
#pragma unroll
    for (int r = 0; r < 4; ++r) {
      const int qg = q0 + wr * 16 + g * 4 + r;
      const bool ok = (jcol <= qg) && (jcol > qg - WINDOW);
      s[r] = ok ? sacc[r] : -1e30f;
      float m = s[r];
#pragma unroll
      for (int off = 1; off < 16; off <<= 1) m = fmaxf(m, __shfl_xor(m, off, 64));
      mx[r] = m;
    }
    if (c == 0) {
#pragma unroll
      for (int r = 0; r < 4; ++r) wmax[wc][wr * 16 + g * 4 + r] = mx[r];
    }
    __syncthreads();  // B

    // exp + P bf16 split to LDS + col-half sums
#pragma unroll
    for (int r = 0; r < 4; ++r) {
      const int row = wr * 16 + g * 4 + r;
      const float mt = fmaxf(wmax[0][row], wmax[1][row]);
      const float mn = fmaxf(mrow[par][row], mt);
      const float p = (s[r] > -1e29f) ? expf(s[r] - mn) : 0.0f;
      float ps = p;
#pragma unroll
      for (int off = 1; off < 16; off <<= 1) ps += __shfl_xor(ps, off, 64);
      if (c == 0) wsum[wc][row] = ps;
      ushort h, l2; split3(p, h, l2);
      Ph[row][wc * 16 + c] = h;
      Pl[row][wc * 16 + c] = l2;
    }
    __syncthreads();  // C

    // m/l state update into par^1 (concurrent with PV below)
    if (tid < 32) {
      const float mt = fmaxf(wmax[0][tid], wmax[1][tid]);
      const float mo = mrow[par][tid];
      const float mn = fmaxf(mo, mt);
      mrow[par ^ 1][tid] = mn;
      lrow[par ^ 1][tid] = lrow[par][tid] * expf(mo - mn) + wsum[0][tid] + wsum[1][tid];
    }
    // PV: this wave owns output cols [w*32, w*32+32), all 32 rows
#pragma unroll
    for (int rh = 0; rh < 2; ++rh) {
      float sc[4];
#pragma unroll
      for (int r = 0; r < 4; ++r) {
        const int row = rh * 16 + g * 4 + r;
        const float mt = fmaxf(wmax[0][row], wmax[1][row]);
        const float mo = mrow[par][row];
        sc[r] = expf(mo - fmaxf(mo, mt));
      }
#pragma unroll
      for (int jt = 0; jt < 2; ++jt)
#pragma unroll
        for (int r = 0; r < 4; ++r) oacc[rh][jt][r] *= sc[r];
      const bf16x8s pah = *(const bf16x8s*)&Ph[rh * 16 + c][g * 8];
      const bf16x8s pal = *(const bf16x8s*)&Pl[rh * 16 + c][g * 8];
      oacc[rh][0] = __builtin_amdgcn_mfma_f32_16x16x32_bf16(pah, vh0, oacc[rh][0], 0, 0, 0);
      oacc[rh][0] = __builtin_amdgcn_mfma_f32_16x16x32_bf16(pal, vh0, oacc[rh][0], 0, 0, 0);
      oacc[rh][0] = __builtin_amdgcn_mfma_f32_16x16x32_bf16(pah, vl0, oacc[rh][0], 0, 0, 0);
      oacc[rh][1] = __builtin_amdgcn_mfma_f32_16x16x32_bf16(pah, vh1, oacc[rh][1], 0, 0, 0);
      oacc[rh][1] = __builtin_amdgcn_mfma_f32_16x16x32_bf16(pal, vh1, oacc[rh][1], 0, 0, 0);
      oacc[rh][1] = __builtin_amdgcn_mfma_f32_16x16x32_bf16(pah, vl1, oacc[rh][1], 0, 0, 0);
    }
    __syncthreads();  // D (protects Ph/Pl/wmax/wsum for next tile)
    par ^= 1;
  }

  // normalize + 2-plane pack out
#pragma unroll
  for (int rh = 0; rh < 2; ++rh) {
#pragma unroll
    for (int r = 0; r < 4; ++r) {
      const int row = rh * 16 + g * 4 + r;
      const float li = 1.0f / lrow[par][row];
      const int qg = q0 + row;
      ushort* base = atp + (size_t)(b * TT + qg) * HDIM + hh * 128;
#pragma unroll
      for (int jt = 0; jt < 2; ++jt) {
        const int d = w * 32 + jt * 16 + c;
        ushort h, l2; split3(oacc[rh][jt][r] * li, h, l2);
        base[d] = h;
        base[PLANE_X + d] = l2;
      }
    }
  }
}

// ---------------- residual + LayerNorm (+ 2-plane pack out) ----------------
template <int HAS_RES>
__global__ __launch_bounds__(128) void ln_kernel(
    const float* __restrict__ x, const float* __restrict__ r,
    const float* __restrict__ g, const float* __restrict__ be,
    float* __restrict__ out, ushort* __restrict__ xp) {
  const int row = blockIdx.x, tid = threadIdx.x;
  float4 v = ((const float4*)(x + (size_t)row * HDIM))[tid];
  if (HAS_RES) {
    const float4 rv = ((const float4*)(r + (size_t)row * HDIM))[tid];
    v.x += rv.x; v.y += rv.y; v.z += rv.z; v.w += rv.w;
  }
  __shared__ float red[2];
  float s = v.x + v.y + v.z + v.w;
  s = wred_sum(s);
  if ((tid & 63) == 0) red[tid >> 6] = s;
  __syncthreads();
  const float mean = (red[0] + red[1]) * (1.0f / 512.0f);
  const float dx = v.x - mean, dy = v.y - mean, dz = v.z - mean, dw = v.w - mean;
  float s2 = dx * dx + dy * dy + dz * dz + dw * dw;
  __syncthreads();
  s2 = wred_sum(s2);
  if ((tid & 63) == 0) red[tid >> 6] = s2;
  __syncthreads();
  const float var = (red[0] + red[1]) * (1.0f / 512.0f);
  const float inv = 1.0f / sqrtf(var + 1e-5f);
  const float4 gv = ((const float4*)g)[tid];
  const float4 bv = ((const float4*)be)[tid];
  float4 o;
  o.x = dx * inv * gv.x + bv.x;
  o.y = dy * inv * gv.y + bv.y;
  o.z = dz * inv * gv.z + bv.z;
  o.w = dw * inv * gv.w + bv.w;
  ((float4*)(out + (size_t)row * HDIM))[tid] = o;
  ushort4 h4, l4;
  split3(o.x, h4.x, l4.x); split3(o.y, h4.y, l4.y);
  split3(o.z, h4.z, l4.z); split3(o.w, h4.w, l4.w);
  ushort* basep = xp + (size_t)row * HDIM + tid * 4;
  *(ushort4*)basep = h4;
  *(ushort4*)(basep + PLANE_X) = l4;
}

// ---------------- fused me3 projection + SSE loss partials ----------------
__global__ __launch_bounds__(256) void head_loss_kernel(
    const float* __restrict__ hme, const float* __restrict__ w3,
    const float* __restrict__ b3, const float* __restrict__ y,
    float* __restrict__ partials) {
  const int row = blockIdx.x;
  const int b = row >> 11, t = row & 2047;
  const int tid = threadIdx.x;
  __shared__ __align__(16) float hl[512];
  __shared__ float acc8[8];
  ((float2*)hl)[tid] = ((const float2*)(hme + (size_t)row * HDIM))[tid];
  __syncthreads();
  const int d = tid >> 5, l32 = tid & 31;
  float s = 0.0f;
  for (int k = l32; k < 512; k += 32) s += hl[k] * w3[k * 8 + d];
#pragma unroll
  for (int off = 16; off; off >>= 1) s += __shfl_xor(s, off, 64);
  if (l32 == 0) {
    const float yh = s + b3[d];
    const float diff = yh - y[((b << 3) + d) * TT + t];
    acc8[d] = diff * diff;
  }
  __syncthreads();
  if (tid == 0) {
    float tot = 0.0f;
#pragma unroll
    for (int i = 0; i < 8; ++i) tot += acc8[i];
    partials[row] = tot;
  }
}

__global__ __launch_bounds__(256) void reduce_kernel(
    const float* __restrict__ partials, float* __restrict__ out, int n) {
  float s = 0.0f;
  for (int i = threadIdx.x; i < n; i += 256) s += partials[i];
  s = wred_sum(s);
  __shared__ float red[4];
  if ((threadIdx.x & 63) == 0) red[threadIdx.x >> 6] = s;
  __syncthreads();
  if (threadIdx.x == 0) out[0] = red[0] + red[1] + red[2] + red[3];
}

// ---------------- host ----------------
extern "C" void kernel_launch(void* const* d_in, const int* in_sizes, int n_in,
                              void* d_out, int out_size, void* d_ws, size_t ws_size,
                              hipStream_t stream) {
  (void)in_sizes; (void)n_in; (void)out_size; (void)ws_size;
  const float* u     = (const float*)d_in[0];
  const float* y     = (const float*)d_in[1];
  const float* W_in  = (const float*)d_in[2];
  const float* b_in  = (const float*)d_in[3];
  const float* qkv_w = (const float*)d_in[4];
  const float* qkv_b = (const float*)d_in[5];
  const float* out_w = (const float*)d_in[6];
  const float* out_b = (const float*)d_in[7];
  const float* ff1_w = (const float*)d_in[8];
  const float* ff1_b = (const float*)d_in[9];
  const float* ff2_w = (const float*)d_in[10];
  const float* ff2_b = (const float*)d_in[11];
  const float* ln1_g = (const float*)d_in[12];
  const float* ln1_b = (const float*)d_in[13];
  const float* ln2_g = (const float*)d_in[14];
  const float* ln2_b = (const float*)d_in[15];
  const float* lnf_g = (const float*)d_in[16];
  const float* lnf_b = (const float*)d_in[17];
  const float* xm1_w = (const float*)d_in[18];
  const float* xm1_b = (const float*)d_in[19];
  const float* xm2_w = (const float*)d_in[20];
  const float* xm2_b = (const float*)d_in[21];
  const float* me1_w = (const float*)d_in[22];
  const float* me1_b = (const float*)d_in[23];
  const float* me2_w = (const float*)d_in[24];
  const float* me2_b = (const float*)d_in[25];
  const float* me3_w = (const float*)d_in[26];
  const float* me3_b = (const float*)d_in[27];

  const int M = BB * TT;  // 8192
  char* ws = (char*)d_ws;
  float*  X    = (float*)(ws);                        // 16 MB [8192,512] f32
  float*  PRJ  = (float*)(ws + ((size_t)16 << 20));   // 16 MB [8192,512] f32
  ushort* BIGp = (ushort*)(ws + ((size_t)32 << 20));  // 64 MB: QKV packs / FF pack
  ushort* PK1  = (ushort*)(ws + ((size_t)96 << 20));  // 16 MB: activation pack (2 planes)
  ushort* WSCR = (ushort*)(ws + ((size_t)112 << 20)); //  8 MB: weight packs
  float*  XM   = (float*)(ws + ((size_t)120 << 20));  // 512 KB [8192,16]
  float*  PART = (float*)(ws + ((size_t)121 << 20));  // 32 KB

  embed_kernel<<<M, 256, 0, stream>>>(u, y, W_in, b_in, X, PK1);

  for (int l = 0; l < LAYERS; ++l) {
    packL_kernel<<<2048, 256, 0, stream>>>(
        qkv_w + (size_t)l * 512 * 1536, out_w + (size_t)l * 512 * 512,
        ff1_w + (size_t)l * 512 * 2048, WSCR);
    gemm_mfma<0, 2><<<dim3(12, 64), 256, 0, stream>>>(
        PK1, PK1 + PLANE_X, WSCR, WSCR + 786432, qkv_b + l * 1536,
        nullptr, nullptr, 0, BIGp, M, 1536, 512);
    attn_mfma<<<dim3(TT / 32, NH, BB), 256, 0, stream>>>(BIGp, PK1);
    gemm_mfma<0, 0><<<dim3(4, 64), 256, 0, stream>>>(
        PK1, PK1 + PLANE_X, WSCR + 1572864, WSCR + 1835008, out_b + l * 512,
        PRJ, nullptr, 0, nullptr, M, 512, 512);
    ln_kernel<1><<<M, 128, 0, stream>>>(X, PRJ, ln1_g + l * 512, ln1_b + l * 512, X, PK1);
    gemm_mfma<1, 1><<<dim3(16, 64), 256, 0, stream>>>(
        PK1, PK1 + PLANE_X, WSCR + 2097152, WSCR + 3145728, ff1_b + l * 2048,
        nullptr, BIGp, PLANE_FF, nullptr, M, 2048, 512);
    packF_kernel<<<1024, 256, 0, stream>>>(ff2_w + (size_t)l * 2048 * 512, WSCR);
    gemm_mfma<0, 0><<<dim3(4, 64), 256, 0, stream>>>(
        BIGp, BIGp + PLANE_FF, WSCR, WSCR + 1048576, ff2_b + l * 512,
        PRJ, nullptr, 0, nullptr, M, 512, 2048);
    ln_kernel<1><<<M, 128, 0, stream>>>(X, PRJ, ln2_g + l * 512, ln2_b + l * 512, X, PK1);
  }
  ln_kernel<0><<<M, 128, 0, stream>>>(X, nullptr, lnf_g, lnf_b, X, PK1);

  packH_kernel<<<512, 256, 0, stream>>>(xm1_w, me2_w, WSCR);
  gemm_mfma<1, 0><<<dim3(4, 64), 256, 0, stream>>>(
      PK1, PK1 + PLANE_X, WSCR, WSCR + 262144, xm1_b,
      PRJ, nullptr, 0, nullptr, M, 512, 512);
  gemm_bias<0, 0><<<dim3(1, 64), 256, 0, stream>>>(PRJ, xm2_w, xm2_b, XM, nullptr, 0, M, 16, 512);
  gemm_bias<1, 1><<<dim3(8, 64), 256, 0, stream>>>(XM, me1_w, me1_b, nullptr, PK1, PLANE_X, M, 512, 16);
  gemm_mfma<1, 0><<<dim3(4, 64), 256, 0, stream>>>(
      PK1, PK1 + PLANE_X, WSCR + 524288, WSCR + 786432, me2_b,
      PRJ, nullptr, 0, nullptr, M, 512, 512);
  head_loss_kernel<<<M, 256, 0, stream>>>(PRJ, me3_w, me3_b, y, PART);
  reduce_kernel<<<1, 256, 0, stream>>>(PART, (float*)d_out, M);
}

// Round 5
// 2146.632 us; speedup vs baseline: 12.2323x; 1.1067x over previous
//
#include <hip/hip_runtime.h>
#include <cstdint>
#include <cstddef>

#define TT 2048
#define BB 4
#define HDIM 512
#define NH 4
#define LAYERS 4
#define WINDOW 606

#define PLANE_QK 4194304ull   // 16*2048*128
#define PLANE_X  4194304ull   // 8192*512
#define PLANE_FF 16777216ull  // 8192*2048

typedef __attribute__((ext_vector_type(8))) short bf16x8s;
typedef __attribute__((ext_vector_type(4))) float f32x4;

// ---------------- helpers ----------------
__device__ __forceinline__ float wred_sum(float v) {
#pragma unroll
  for (int off = 32; off; off >>= 1) v += __shfl_xor(v, off, 64);
  return v;
}
__device__ __forceinline__ float gelu_exact(float x) {
  return 0.5f * x * (1.0f + erff(x * 0.70710678118654752f));
}
__device__ __forceinline__ ushort bf16_rne(float v) {
  uint32_t u = __float_as_uint(v);
  u += 0x7FFFu + ((u >> 16) & 1u);
  return (ushort)(u >> 16);
}
__device__ __forceinline__ void split3(float v, ushort& h, ushort& l) {
  h = bf16_rne(v);
  const float hf = __uint_as_float(((uint32_t)h) << 16);
  l = bf16_rne(v - hf);
}
__device__ __forceinline__ void gld_lds16(const void* g, void* l) {
  __builtin_amdgcn_global_load_lds(
      (const __attribute__((address_space(1))) uint32_t*)g,
      (__attribute__((address_space(3))) uint32_t*)l, 16, 0, 0);
}

// ---------------- input embed: u_aug @ W_in + b + pos_enc (f32 out + 2-plane pack) ----------------
__global__ __launch_bounds__(256) void embed_kernel(
    const float* __restrict__ u, const float* __restrict__ y,
    const float* __restrict__ W_in, const float* __restrict__ b_in,
    float* __restrict__ X, ushort* __restrict__ xp) {
  const int row = blockIdx.x;
  const int b = row >> 11;
  const int t = row & 2047;
  const int tid = threadIdx.x;
  __shared__ float ua[24];
  if (tid < 8)       ua[tid] = u[((b << 3) + tid) * TT + t];
  else if (tid < 16) ua[tid] = 0.0f;   // y_aug (phy rollout) is zeros
  else if (tid < 24) ua[tid] = (t < 30) ? y[((b << 3) + (tid - 16)) * TT + t] : 0.0f;
  __syncthreads();
#pragma unroll
  for (int c0 = 0; c0 < 2; ++c0) {
    const int c = c0 * 256 + tid;
    float s = b_in[c];
#pragma unroll
    for (int k = 0; k < 24; ++k) s += ua[k] * W_in[k * HDIM + c];
    const float dv = expf(-0.0179889460337f * (float)(c & ~1));
    const float arg = (float)t * dv;
    s += (c & 1) ? cosf(arg) : sinf(arg);
    X[(size_t)row * HDIM + c] = s;
    ushort h, l2; split3(s, h, l2);
    xp[(size_t)row * HDIM + c] = h;
    xp[PLANE_X + (size_t)row * HDIM + c] = l2;
  }
}

// ---------------- weight pack: W[K][N] f32 -> planes [N][K] bf16 hi @0, lo @N*K ----------------
__device__ __forceinline__ void pack_tile(float (*tile)[33],
    const float* __restrict__ W, ushort* __restrict__ Wp,
    int K, int N, int bk, int bn, int tid) {
  const int i0 = tid >> 5, j = tid & 31;
#pragma unroll
  for (int i = 0; i < 4; ++i) {
    const int kk = i0 + i * 8;
    tile[kk][j] = W[(size_t)(bk + kk) * N + bn + j];
  }
  __syncthreads();
  const size_t NK = (size_t)N * K;
#pragma unroll
  for (int i = 0; i < 4; ++i) {
    const int nn = i0 + i * 8;
    const float v = tile[j][nn];
    ushort h, l2; split3(v, h, l2);
    ushort* base = Wp + (size_t)(bn + nn) * K + bk + j;
    base[0] = h; base[NK] = l2;
  }
}

__global__ __launch_bounds__(256) void packL_kernel(
    const float* __restrict__ qkvw, const float* __restrict__ outw,
    const float* __restrict__ ff1w, ushort* __restrict__ Wp) {
  __shared__ float tile[32][33];
  int i = blockIdx.x;
  if (i < 768) {
    pack_tile(tile, qkvw, Wp, 512, 1536, (i & 15) * 32, (i >> 4) * 32, threadIdx.x);
  } else if (i < 1024) {
    i -= 768;
    pack_tile(tile, outw, Wp + 1572864, 512, 512, (i & 15) * 32, (i >> 4) * 32, threadIdx.x);
  } else {
    i -= 1024;
    pack_tile(tile, ff1w, Wp + 2097152, 512, 2048, (i & 15) * 32, (i >> 4) * 32, threadIdx.x);
  }
}

__global__ __launch_bounds__(256) void packF_kernel(
    const float* __restrict__ ff2w, ushort* __restrict__ Wp) {
  __shared__ float tile[32][33];
  const int i = blockIdx.x;
  pack_tile(tile, ff2w, Wp, 2048, 512, (i & 63) * 32, (i >> 6) * 32, threadIdx.x);
}

__global__ __launch_bounds__(256) void packH_kernel(
    const float* __restrict__ xm1w, const float* __restrict__ me2w,
    ushort* __restrict__ Wp) {
  __shared__ float tile[32][33];
  int i = blockIdx.x;
  if (i < 256) pack_tile(tile, xm1w, Wp, 512, 512, (i & 15) * 32, (i >> 4) * 32, threadIdx.x);
  else { i -= 256; pack_tile(tile, me2w, Wp + 524288, 512, 512, (i & 15) * 32, (i >> 4) * 32, threadIdx.x); }
}

// ---------------- bf16 MFMA GEMM: C = A * B^T with 3-term hi/lo split ----------------
// A planes [M][K] (Ah, Al), B planes [N][K] (Bh, Bl). terms: Ah*Bh + Al*Bh + Ah*Bl.
// OUTMODE: 0 = f32 C; 1 = 2-plane bf16 pack Cp (+cplane); 2 = QKV special (Wq).
// RM: block rows (128 or 64). BN fixed 128, BK=32.
template <int ACT, int OUTMODE, int RM>
__global__ __launch_bounds__(256) void gemm_mfma(
    const ushort* __restrict__ Ah, const ushort* __restrict__ Al,
    const ushort* __restrict__ Bh, const ushort* __restrict__ Bl,
    const float* __restrict__ bias,
    float* __restrict__ C, ushort* __restrict__ Cp, size_t cplane,
    ushort* __restrict__ Wq, int M, int N, int K) {
  constexpr int IA = RM / 32;         // A row-frags per wave
  constexpr int JA = RM / 64;         // A staging issues per thread
  __shared__ ushort Als[RM * 32];     // [RM][32]
  __shared__ ushort Bls[4096];        // [128][32]
  __shared__ float biasL[128];
  const int tid = threadIdx.x;
  const int bn = blockIdx.x * 128, bm = blockIdx.y * RM;
  const int w = tid >> 6, ln = tid & 63;
  const int wr = (w >> 1) * (RM / 2), wc = (w & 1) * 64;
  const int c = ln & 15, g = ln >> 4;
  if (tid < 128) biasL[tid] = bias[bn + tid];

  const int srow = tid >> 2;          // staging row within 64-row chunk
  const int scol = (tid & 3) * 8;     // staging col (ushorts)

  f32x4 acc[IA][4] = {};
#pragma unroll
  for (int term = 0; term < 3; ++term) {
    const ushort* Ag = (term == 1) ? Al : Ah;
    const ushort* Bg = (term == 2) ? Bl : Bh;
    for (int k0 = 0; k0 < K; k0 += 32) {
#pragma unroll
      for (int j = 0; j < JA; ++j) {
        const int off = j * 4096 + tid * 16;
        gld_lds16(Ag + (size_t)(bm + j * 64 + srow) * K + k0 + scol, (char*)Als + off);
      }
#pragma unroll
      for (int j = 0; j < 2; ++j) {
        const int off = j * 4096 + tid * 16;
        gld_lds16(Bg + (size_t)(bn + j * 64 + srow) * K + k0 + scol, (char*)Bls + off);
      }
      __syncthreads();
      bf16x8s fa[IA], fb[4];
#pragma unroll
      for (int i = 0; i < IA; ++i)
        fa[i] = *(const bf16x8s*)&Als[(wr + i * 16 + c) * 32 + g * 8];
#pragma unroll
      for (int i = 0; i < 4; ++i)
        fb[i] = *(const bf16x8s*)&Bls[(wc + i * 16 + c) * 32 + g * 8];
#pragma unroll
      for (int i = 0; i < IA; ++i)
#pragma unroll
        for (int j = 0; j < 4; ++j)
          acc[i][j] = __builtin_amdgcn_mfma_f32_16x16x32_bf16(fa[i], fb[j], acc[i][j], 0, 0, 0);
      __syncthreads();
    }
  }
  // epilogue: C/D layout col=lane&15, row=(lane>>4)*4+reg [m89-verified]
  // Q pre-scale folds 1/sqrt(128) * log2(e) so attention can use exp2.
  const float qscale = 0.08838834764831845f * 1.44269504088896341f;
#pragma unroll
  for (int i = 0; i < IA; ++i) {
    const int grow0 = bm + wr + i * 16 + g * 4;
#pragma unroll
    for (int j = 0; j < 4; ++j) {
      const int gcol = bn + wc + j * 16 + c;
      const float bv = biasL[wc + j * 16 + c];
      if (OUTMODE == 2) {
        const int bq = grow0 >> 11, tl = grow0 & 2047;
        if (bn < 512) {            // Q: scaled, row-major [bh][t][128]
          const int hh = gcol >> 7, d = gcol & 127;
          ushort* dst = Wq + ((size_t)(bq * NH + hh) * TT + tl) * 128 + d;
#pragma unroll
          for (int r = 0; r < 4; ++r) {
            ushort h, l2; split3((acc[i][j][r] + bv) * qscale, h, l2);
            dst[(size_t)r * 128] = h;
            dst[PLANE_QK + (size_t)r * 128] = l2;
          }
        } else if (bn < 1024) {    // K: row-major [bh][t][128]
          const int hh = (gcol - 512) >> 7, d = gcol & 127;
          ushort* dst = Wq + 2 * PLANE_QK + ((size_t)(bq * NH + hh) * TT + tl) * 128 + d;
#pragma unroll
          for (int r = 0; r < 4; ++r) {
            ushort h, l2; split3(acc[i][j][r] + bv, h, l2);
            dst[(size_t)r * 128] = h;
            dst[PLANE_QK + (size_t)r * 128] = l2;
          }
        } else {                   // V: transposed [bh][d][t]
          const int hh = (gcol - 1024) >> 7, d = gcol & 127;
          ushort4 h4, l4;
          split3(acc[i][j][0] + bv, h4.x, l4.x);
          split3(acc[i][j][1] + bv, h4.y, l4.y);
          split3(acc[i][j][2] + bv, h4.z, l4.z);
          split3(acc[i][j][3] + bv, h4.w, l4.w);
          ushort* dst = Wq + 4 * PLANE_QK + ((size_t)(bq * NH + hh) * 128 + d) * TT + tl;
          *(ushort4*)dst = h4;
          *(ushort4*)(dst + PLANE_QK) = l4;
        }
      } else {
#pragma unroll
        for (int r = 0; r < 4; ++r) {
          float v = acc[i][j][r] + bv;
          if (ACT) v = gelu_exact(v);
          if (OUTMODE == 1) {
            ushort h, l2; split3(v, h, l2);
            ushort* base = Cp + (size_t)(grow0 + r) * N + gcol;
            base[0] = h; base[cplane] = l2;
          } else {
            C[(size_t)(grow0 + r) * N + gcol] = v;
          }
        }
      }
    }
  }
}

// ---------------- fp32 tiled GEMM (small shapes: xm2, me1) ----------------
template <int ACT, int PACK>
__global__ __launch_bounds__(256) void gemm_bias(
    const float* __restrict__ A, const float* __restrict__ B,
    const float* __restrict__ bias, float* __restrict__ C,
    ushort* __restrict__ Cp, size_t cplane, int M, int N, int K) {
  __shared__ float As[16][132];
  __shared__ float Bs[16][64];
  const int bm = blockIdx.y * 128;
  const int bn = blockIdx.x * 64;
  const int tid = threadIdx.x;
  const int tx = tid & 15, ty = tid >> 4;
  float acc[8][4] = {};
  for (int k0 = 0; k0 < K; k0 += 16) {
#pragma unroll
    for (int i = 0; i < 8; ++i) {
      const int idx = i * 256 + tid;
      const int m = idx >> 4, k = idx & 15;
      As[k][m] = A[(size_t)(bm + m) * K + k0 + k];
    }
#pragma unroll
    for (int i = 0; i < 4; ++i) {
      const int idx = i * 256 + tid;
      const int k = idx >> 6, n = idx & 63;
      Bs[k][n] = (bn + n < N) ? B[(size_t)(k0 + k) * N + bn + n] : 0.0f;
    }
    __syncthreads();
#pragma unroll
    for (int kk = 0; kk < 16; ++kk) {
      float a[8], bb[4];
#pragma unroll
      for (int i = 0; i < 8; ++i) a[i] = As[kk][ty * 8 + i];
#pragma unroll
      for (int j = 0; j < 4; ++j) bb[j] = Bs[kk][tx * 4 + j];
#pragma unroll
      for (int i = 0; i < 8; ++i)
#pragma unroll
        for (int j = 0; j < 4; ++j) acc[i][j] += a[i] * bb[j];
    }
    __syncthreads();
  }
#pragma unroll
  for (int i = 0; i < 8; ++i) {
    const int m = bm + ty * 8 + i;
#pragma unroll
    for (int j = 0; j < 4; ++j) {
      const int n = bn + tx * 4 + j;
      if (n < N) {
        float v = acc[i][j] + bias[n];
        if (ACT) v = gelu_exact(v);
        if (PACK) {
          ushort h, l2; split3(v, h, l2);
          ushort* base = Cp + (size_t)m * N + n;
          base[0] = h; base[cplane] = l2;
        } else {
          C[(size_t)m * N + n] = v;
        }
      }
    }
  }
}

// ---------------- MFMA flash sliding-window attention (swapped QK^T, XCD swizzle) ----------------
// QKVp planes: Qh|Ql|Kh|Kl|Vth|Vtl, each PLANE_QK. Q/K: [bh][t][128]; Vt: [bh][d][t].
// Q is pre-scaled by (1/sqrt(dh))*log2e, so softmax uses exp2.
// Scores computed as mfma(K,Q): lane holds 4 k's for ONE q -> cheap row reduce.
__global__ __launch_bounds__(256) void attn_mfma(
    const ushort* __restrict__ QKVp, ushort* __restrict__ atp) {
  // XCD-aware swizzle: 8 XCDs, 1024 blocks -> each XCD gets 2 full (b,h) q-ranges
  const int bid = blockIdx.x;
  const int lid = (bid & 7) * 128 + (bid >> 3);
  const int q0 = (lid & 63) * 32;
  const int bh = lid >> 6;
  const int b = bh >> 2, hh = bh & 3;
  const int tid = threadIdx.x;
  const int w = tid >> 6, lane = tid & 63;
  const int c = lane & 15, g = lane >> 4;
  const int wr = w >> 1, wc = w & 1;

  __shared__ ushort Ph[32][40], Pl[32][40];
  __shared__ float wmax[2][32], wsum[2][32];
  __shared__ float mrow[2][32], lrow[2][32];

  const ushort* Qh = QKVp;
  const ushort* Ql = QKVp + PLANE_QK;
  const ushort* Kh = QKVp + 2 * PLANE_QK;
  const ushort* Kl = QKVp + 3 * PLANE_QK;
  const ushort* Vh = QKVp + 4 * PLANE_QK;
  const ushort* Vl = QKVp + 5 * PLANE_QK;

  const size_t qkbase = (size_t)bh * TT * 128;
  const size_t vtbase = (size_t)bh * 128 * TT;

  // Q fragments (B-operand rows = q0 + wr*16 + c), held for the whole kernel
  bf16x8s qh[4], ql[4];
  {
    const ushort* qr = Qh + qkbase + (size_t)(q0 + wr * 16 + c) * 128 + g * 8;
    const ushort* qr2 = Ql + qkbase + (size_t)(q0 + wr * 16 + c) * 128 + g * 8;
#pragma unroll
    for (int kc = 0; kc < 4; ++kc) {
      qh[kc] = *(const bf16x8s*)(qr + kc * 32);
      ql[kc] = *(const bf16x8s*)(qr2 + kc * 32);
    }
  }

  if (tid < 32) { mrow[0][tid] = -1e30f; lrow[0][tid] = 0.0f; }
  __syncthreads();

  f32x4 oacc[2][2] = {};
  int par = 0;
  int lo_ = q0 - (WINDOW - 1); if (lo_ < 0) lo_ = 0;
  const int k_first = lo_ & ~31;
  const int qg = q0 + wr * 16 + c;       // this lane's query (for mask)
  const int qrow = wr * 16 + c;          // local row for softmax state

  for (int k0 = k_first; k0 <= q0; k0 += 32) {
    // V fragments (prefetch; consumed after barrier C)
    const bf16x8s vh0 = *(const bf16x8s*)(Vh + vtbase + (size_t)(w * 32 + c) * TT + k0 + g * 8);
    const bf16x8s vh1 = *(const bf16x8s*)(Vh + vtbase + (size_t)(w * 32 + 16 + c) * TT + k0 + g * 8);
    const bf16x8s vl0 = *(const bf16x8s*)(Vl + vtbase + (size_t)(w * 32 + c) * TT + k0 + g * 8);
    const bf16x8s vl1 = *(const bf16x8s*)(Vl + vtbase + (size_t)(w * 32 + 16 + c) * TT + k0 + g * 8);

    // scores (swapped): D[k_local][q_local]; wave quadrant k in [wc*16,..), q in [wr*16,..)
    f32x4 sacc = {};
    {
      const ushort* kr = Kh + qkbase + (size_t)(k0 + wc * 16 + c) * 128 + g * 8;
      const ushort* kr2 = Kl + qkbase + (size_t)(k0 + wc * 16 + c) * 128 + g * 8;
      bf16x8s kh[4], kl[4];
#pragma unroll
      for (int kc = 0; kc < 4; ++kc) {
        kh[kc] = *(const bf16x8s*)(kr + kc * 32);
        kl[kc] = *(const bf16x8s*)(kr2 + kc * 32);
      }
#pragma unroll
      for (int kc = 0; kc < 4; ++kc)
        sacc = __builtin_amdgcn_mfma_f32_16x16x32_bf16(kh[kc], qh[kc], sacc, 0, 0, 0);
#pragma unroll
      for (int kc = 0; kc < 4; ++kc)
        sacc = __builtin_amdgcn_mfma_f32_16x16x32_bf16(kl[kc], qh[kc], sacc, 0, 0, 0);
#pragma unroll
      for (int kc = 0; kc < 4; ++kc)
        sacc = __builtin_amdgcn_mfma_f32_16x16x32_bf16(kh[kc], ql[kc], sacc, 0, 0, 0);
    }
    // mask (lane's 4 regs = 4 consecutive k's, one q) + cheap row max
    float s[4];
    float m4 = -1e30f;
#pragma unroll
    for (int r = 0; r < 4; ++r) {
      const int kj = k0 + wc * 16 + g * 4 + r;
      const bool ok = (kj <= qg) && (kj > qg - WINDOW);
      s[r] = ok ? sacc[r] : -1e30f;
      m4 = fmaxf(m4, s[r]);
    }
    m4 = fmaxf(m4, __shfl_xor(m4, 16, 64));
    m4 = fmaxf(m4, __shfl_xor(m4, 32, 64));
    if (lane < 16) wmax[wc][qrow] = m4;
    __syncthreads();  // B

    // exp2 + P split to LDS + row sums
    {
      const float mt = fmaxf(wmax[0][qrow], wmax[1][qrow]);
      const float mn = fmaxf(mrow[par][qrow], mt);
      float pv[4];
      float ps = 0.0f;
#pragma unroll
      for (int r = 0; r < 4; ++r) {
        pv[r] = (s[r] > -1e29f) ? exp2f(s[r] - mn) : 0.0f;
        ps += pv[r];
      }
      ps += __shfl_xor(ps, 16, 64);
      ps += __shfl_xor(ps, 32, 64);
      if (lane < 16) wsum[wc][qrow] = ps;
      ushort4 h4, l4;
      split3(pv[0], h4.x, l4.x); split3(pv[1], h4.y, l4.y);
      split3(pv[2], h4.z, l4.z); split3(pv[3], h4.w, l4.w);
      *(ushort4*)&Ph[qrow][wc * 16 + g * 4] = h4;
      *(ushort4*)&Pl[qrow][wc * 16 + g * 4] = l4;
    }
    __syncthreads();  // C

    // m/l state update into par^1 (concurrent with PV below)
    if (tid < 32) {
      const float mt = fmaxf(wmax[0][tid], wmax[1][tid]);
      const float mo = mrow[par][tid];
      const float mn = fmaxf(mo, mt);
      mrow[par ^ 1][tid] = mn;
      lrow[par ^ 1][tid] = lrow[par][tid] * exp2f(mo - mn) + wsum[0][tid] + wsum[1][tid];
    }
    // PV: this wave owns output cols [w*32, w*32+32), all 32 rows
#pragma unroll
    for (int rh = 0; rh < 2; ++rh) {
      float sc[4];
#pragma unroll
      for (int r = 0; r < 4; ++r) {
        const int row = rh * 16 + g * 4 + r;
        const float mt = fmaxf(wmax[0][row], wmax[1][row]);
        const float mo = mrow[par][row];
        sc[r] = exp2f(mo - fmaxf(mo, mt));
      }
#pragma unroll
      for (int jt = 0; jt < 2; ++jt)
#pragma unroll
        for (int r = 0; r < 4; ++r) oacc[rh][jt][r] *= sc[r];
      const bf16x8s pah = *(const bf16x8s*)&Ph[rh * 16 + c][g * 8];
      const bf16x8s pal = *(const bf16x8s*)&Pl[rh * 16 + c][g * 8];
      oacc[rh][0] = __builtin_amdgcn_mfma_f32_16x16x32_bf16(pah, vh0, oacc[rh][0], 0, 0, 0);
      oacc[rh][0] = __builtin_amdgcn_mfma_f32_16x16x32_bf16(pal, vh0, oacc[rh][0], 0, 0, 0);
      oacc[rh][0] = __builtin_amdgcn_mfma_f32_16x16x32_bf16(pah, vl0, oacc[rh][0], 0, 0, 0);
      oacc[rh][1] = __builtin_amdgcn_mfma_f32_16x16x32_bf16(pah, vh1, oacc[rh][1], 0, 0, 0);
      oacc[rh][1] = __builtin_amdgcn_mfma_f32_16x16x32_bf16(pal, vh1, oacc[rh][1], 0, 0, 0);
      oacc[rh][1] = __builtin_amdgcn_mfma_f32_16x16x32_bf16(pah, vl1, oacc[rh][1], 0, 0, 0);
    }
    __syncthreads();  // D (protects Ph/Pl/wmax/wsum for next tile)
    par ^= 1;
  }

  // normalize + 2-plane pack out
#pragma unroll
  for (int rh = 0; rh < 2; ++rh) {
#pragma unroll
    for (int r = 0; r < 4; ++r) {
      const int row = rh * 16 + g * 4 + r;
      const float li = 1.0f / lrow[par][row];
      const int qgo = q0 + row;
      ushort* base = atp + (size_t)(b * TT + qgo) * HDIM + hh * 128;
#pragma unroll
      for (int jt = 0; jt < 2; ++jt) {
        const int d = w * 32 + jt * 16 + c;
        ushort h, l2; split3(oacc[rh][jt][r] * li, h, l2);
        base[d] = h;
        base[PLANE_X + d] = l2;
      }
    }
  }
}

// ---------------- residual + LayerNorm (+ 2-plane pack out) ----------------
template <int HAS_RES>
__global__ __launch_bounds__(128) void ln_kernel(
    const float* __restrict__ x, const float* __restrict__ r,
    const float* __restrict__ g, const float* __restrict__ be,
    float* __restrict__ out, ushort* __restrict__ xp) {
  const int row = blockIdx.x, tid = threadIdx.x;
  float4 v = ((const float4*)(x + (size_t)row * HDIM))[tid];
  if (HAS_RES) {
    const float4 rv = ((const float4*)(r + (size_t)row * HDIM))[tid];
    v.x += rv.x; v.y += rv.y; v.z += rv.z; v.w += rv.w;
  }
  __shared__ float red[2];
  float s = v.x + v.y + v.z + v.w;
  s = wred_sum(s);
  if ((tid & 63) == 0) red[tid >> 6] = s;
  __syncthreads();
  const float mean = (red[0] + red[1]) * (1.0f / 512.0f);
  const float dx = v.x - mean, dy = v.y - mean, dz = v.z - mean, dw = v.w - mean;
  float s2 = dx * dx + dy * dy + dz * dz + dw * dw;
  __syncthreads();
  s2 = wred_sum(s2);
  if ((tid & 63) == 0) red[tid >> 6] = s2;
  __syncthreads();
  const float var = (red[0] + red[1]) * (1.0f / 512.0f);
  const float inv = 1.0f / sqrtf(var + 1e-5f);
  const float4 gv = ((const float4*)g)[tid];
  const float4 bv = ((const float4*)be)[tid];
  float4 o;
  o.x = dx * inv * gv.x + bv.x;
  o.y = dy * inv * gv.y + bv.y;
  o.z = dz * inv * gv.z + bv.z;
  o.w = dw * inv * gv.w + bv.w;
  ((float4*)(out + (size_t)row * HDIM))[tid] = o;
  ushort4 h4, l4;
  split3(o.x, h4.x, l4.x); split3(o.y, h4.y, l4.y);
  split3(o.z, h4.z, l4.z); split3(o.w, h4.w, l4.w);
  ushort* basep = xp + (size_t)row * HDIM + tid * 4;
  *(ushort4*)basep = h4;
  *(ushort4*)(basep + PLANE_X) = l4;
}

// ---------------- fused me3 projection + SSE loss partials ----------------
__global__ __launch_bounds__(256) void head_loss_kernel(
    const float* __restrict__ hme, const float* __restrict__ w3,
    const float* __restrict__ b3, const float* __restrict__ y,
    float* __restrict__ partials) {
  const int row = blockIdx.x;
  const int b = row >> 11, t = row & 2047;
  const int tid = threadIdx.x;
  __shared__ __align__(16) float hl[512];
  __shared__ float acc8[8];
  ((float2*)hl)[tid] = ((const float2*)(hme + (size_t)row * HDIM))[tid];
  __syncthreads();
  const int d = tid >> 5, l32 = tid & 31;
  float s = 0.0f;
  for (int k = l32; k < 512; k += 32) s += hl[k] * w3[k * 8 + d];
#pragma unroll
  for (int off = 16; off; off >>= 1) s += __shfl_xor(s, off, 64);
  if (l32 == 0) {
    const float yh = s + b3[d];
    const float diff = yh - y[((b << 3) + d) * TT + t];
    acc8[d] = diff * diff;
  }
  __syncthreads();
  if (tid == 0) {
    float tot = 0.0f;
#pragma unroll
    for (int i = 0; i < 8; ++i) tot += acc8[i];
    partials[row] = tot;
  }
}

__global__ __launch_bounds__(256) void reduce_kernel(
    const float* __restrict__ partials, float* __restrict__ out, int n) {
  float s = 0.0f;
  for (int i = threadIdx.x; i < n; i += 256) s += partials[i];
  s = wred_sum(s);
  __shared__ float red[4];
  if ((threadIdx.x & 63) == 0) red[threadIdx.x >> 6] = s;
  __syncthreads();
  if (threadIdx.x == 0) out[0] = red[0] + red[1] + red[2] + red[3];
}

// ---------------- host ----------------
extern "C" void kernel_launch(void* const* d_in, const int* in_sizes, int n_in,
                              void* d_out, int out_size, void* d_ws, size_t ws_size,
                              hipStream_t stream) {
  (void)in_sizes; (void)n_in; (void)out_size; (void)ws_size;
  const float* u     = (const float*)d_in[0];
  const float* y     = (const float*)d_in[1];
  const float* W_in  = (const float*)d_in[2];
  const float* b_in  = (const float*)d_in[3];
  const float* qkv_w = (const float*)d_in[4];
  const float* qkv_b = (const float*)d_in[5];
  const float* out_w = (const float*)d_in[6];
  const float* out_b = (const float*)d_in[7];
  const float* ff1_w = (const float*)d_in[8];
  const float* ff1_b = (const float*)d_in[9];
  const float* ff2_w = (const float*)d_in[10];
  const float* ff2_b = (const float*)d_in[11];
  const float* ln1_g = (const float*)d_in[12];
  const float* ln1_b = (const float*)d_in[13];
  const float* ln2_g = (const float*)d_in[14];
  const float* ln2_b = (const float*)d_in[15];
  const float* lnf_g = (const float*)d_in[16];
  const float* lnf_b = (const float*)d_in[17];
  const float* xm1_w = (const float*)d_in[18];
  const float* xm1_b = (const float*)d_in[19];
  const float* xm2_w = (const float*)d_in[20];
  const float* xm2_b = (const float*)d_in[21];
  const float* me1_w = (const float*)d_in[22];
  const float* me1_b = (const float*)d_in[23];
  const float* me2_w = (const float*)d_in[24];
  const float* me2_b = (const float*)d_in[25];
  const float* me3_w = (const float*)d_in[26];
  const float* me3_b = (const float*)d_in[27];

  const int M = BB * TT;  // 8192
  char* ws = (char*)d_ws;
  float*  X    = (float*)(ws);                        // 16 MB [8192,512] f32
  float*  PRJ  = (float*)(ws + ((size_t)16 << 20));   // 16 MB [8192,512] f32
  ushort* BIGp = (ushort*)(ws + ((size_t)32 << 20));  // 64 MB: QKV packs / FF pack
  ushort* PK1  = (ushort*)(ws + ((size_t)96 << 20));  // 16 MB: activation pack (2 planes)
  ushort* WSCR = (ushort*)(ws + ((size_t)112 << 20)); //  8 MB: weight packs
  float*  XM   = (float*)(ws + ((size_t)120 << 20));  // 512 KB [8192,16]
  float*  PART = (float*)(ws + ((size_t)121 << 20));  // 32 KB

  embed_kernel<<<M, 256, 0, stream>>>(u, y, W_in, b_in, X, PK1);

  for (int l = 0; l < LAYERS; ++l) {
    packL_kernel<<<2048, 256, 0, stream>>>(
        qkv_w + (size_t)l * 512 * 1536, out_w + (size_t)l * 512 * 512,
        ff1_w + (size_t)l * 512 * 2048, WSCR);
    gemm_mfma<0, 2, 128><<<dim3(12, 64), 256, 0, stream>>>(
        PK1, PK1 + PLANE_X, WSCR, WSCR + 786432, qkv_b + l * 1536,
        nullptr, nullptr, 0, BIGp, M, 1536, 512);
    attn_mfma<<<1024, 256, 0, stream>>>(BIGp, PK1);
    gemm_mfma<0, 0, 64><<<dim3(4, 128), 256, 0, stream>>>(
        PK1, PK1 + PLANE_X, WSCR + 1572864, WSCR + 1835008, out_b + l * 512,
        PRJ, nullptr, 0, nullptr, M, 512, 512);
    ln_kernel<1><<<M, 128, 0, stream>>>(X, PRJ, ln1_g + l * 512, ln1_b + l * 512, X, PK1);
    gemm_mfma<1, 1, 128><<<dim3(16, 64), 256, 0, stream>>>(
        PK1, PK1 + PLANE_X, WSCR + 2097152, WSCR + 3145728, ff1_b + l * 2048,
        nullptr, BIGp, PLANE_FF, nullptr, M, 2048, 512);
    packF_kernel<<<1024, 256, 0, stream>>>(ff2_w + (size_t)l * 2048 * 512, WSCR);
    gemm_mfma<0, 0, 64><<<dim3(4, 128), 256, 0, stream>>>(
        BIGp, BIGp + PLANE_FF, WSCR, WSCR + 1048576, ff2_b + l * 512,
        PRJ, nullptr, 0, nullptr, M, 512, 2048);
    ln_kernel<1><<<M, 128, 0, stream>>>(X, PRJ, ln2_g + l * 512, ln2_b + l * 512, X, PK1);
  }
  ln_kernel<0><<<M, 128, 0, stream>>>(X, nullptr, lnf_g, lnf_b, X, PK1);

  packH_kernel<<<512, 256, 0, stream>>>(xm1_w, me2_w, WSCR);
  gemm_mfma<1, 0, 64><<<dim3(4, 128), 256, 0, stream>>>(
      PK1, PK1 + PLANE_X, WSCR, WSCR + 262144, xm1_b,
      PRJ, nullptr, 0, nullptr, M, 512, 512);
  gemm_bias<0, 0><<<dim3(1, 64), 256, 0, stream>>>(PRJ, xm2_w, xm2_b, XM, nullptr, 0, M, 16, 512);
  gemm_bias<1, 1><<<dim3(8, 64), 256, 0, stream>>>(XM, me1_w, me1_b, nullptr, PK1, PLANE_X, M, 512, 16);
  gemm_mfma<1, 0, 64><<<dim3(4, 128), 256, 0, stream>>>(
      PK1, PK1 + PLANE_X, WSCR + 524288, WSCR + 786432, me2_b,
      PRJ, nullptr, 0, nullptr, M, 512, 512);
  head_loss_kernel<<<M, 256, 0, stream>>>(PRJ, me3_w, me3_b, y, PART);
  reduce_kernel<<<1, 256, 0, stream>>>(PART, (float*)d_out, M);
}